// Round 14
// baseline (208.372 us; speedup 1.0000x reference)
//
#include <hip/hip_runtime.h>
#include <hip/hip_fp16.h>
#include <stdint.h>

typedef _Float16 f16;
typedef _Float16 f16x2 __attribute__((ext_vector_type(2)));
typedef _Float16 f16x4 __attribute__((ext_vector_type(4)));
typedef _Float16 f16x8 __attribute__((ext_vector_type(8)));
typedef __fp16 fp16x2 __attribute__((ext_vector_type(2)));  // cvt_pkrtz return type
typedef float f32x4 __attribute__((ext_vector_type(4)));

#define NB 8
#define NL 2048
#define ND 256
#define QKV_ELEMS (NB * NL * ND)   // 4194304

__device__ __forceinline__ f32x4 mfma16(f16x8 a, f16x8 b, f32x4 c) {
  return __builtin_amdgcn_mfma_f32_16x16x32_f16(a, b, c, 0, 0, 0);
}

// async global->LDS, 16B/lane; LDS dest = wave-uniform base (+lane*16 implicit).
__device__ __forceinline__ void gl_lds16(const void* g, void* l) {
  __builtin_amdgcn_global_load_lds(
      (const __attribute__((address_space(1))) void*)g,
      (__attribute__((address_space(3))) void*)l, 16, 0, 0);
}

// ---------------- K0: transpose+convert weights: WT[m][n][k] = (f16)W_m[k][n]
__global__ void k0_wt(const float* __restrict__ Wq, const float* __restrict__ Wk,
                      const float* __restrict__ Wv, f16* __restrict__ WT) {
  int id = blockIdx.x * 256 + threadIdx.x;  // 0..196607
  int m = id >> 16;
  int r = id & 65535;
  int k = r >> 8, n = r & 255;
  const float* W = (m == 0) ? Wq : (m == 1) ? Wk : Wv;
  WT[m * 65536 + n * 256 + k] = (f16)W[k * 256 + n];
}

// ---------------- K1: projections (fp32 A, f16 MFMA, f16 out). 64 rows/block.
__global__ __launch_bounds__(256) void k1_proj(
    const float* __restrict__ Aq, const float* __restrict__ Ak, const float* __restrict__ Av,
    const f16* __restrict__ WT, f16* __restrict__ Qh, f16* __restrict__ Kh,
    f16* __restrict__ Vh) {
  const int m = blockIdx.y;
  const float* A = (m == 0) ? Aq : (m == 1) ? Ak : Av;
  f16* O = (m == 0) ? Qh : (m == 1) ? Kh : Vh;
  const f16* Wm = WT + m * 65536;
  const int row0 = blockIdx.x * 64;
  const int tid = threadIdx.x;
  const int lane = tid & 63, w = tid >> 6;

  __shared__ f16 Ald[64 * 64];    // [r][k], swizzled ((r&7)<<4) on byte offset
  __shared__ f16 Wld[256 * 64];   // [n][k], swizzled ((n&7)<<4)

  f32x4 acc[16];
#pragma unroll
  for (int i = 0; i < 16; ++i) acc[i] = f32x4{0.f, 0.f, 0.f, 0.f};

  for (int kb = 0; kb < 4; ++kb) {
    __syncthreads();
    {  // stage A tile 64x64 fp32 -> f16
      const int r = tid >> 2, c0 = (tid & 3) * 16;
      const float* src = A + (size_t)(row0 + r) * ND + kb * 64 + c0;
      f16x8 h0, h1;
#pragma unroll
      for (int j = 0; j < 8; ++j) h0[j] = (f16)src[j];
#pragma unroll
      for (int j = 0; j < 8; ++j) h1[j] = (f16)src[8 + j];
      const int sw = (r & 7) << 4;
      *(f16x8*)((char*)Ald + r * 128 + ((c0 * 2) ^ sw)) = h0;
      *(f16x8*)((char*)Ald + r * 128 + ((c0 * 2 + 16) ^ sw)) = h1;
    }
    {  // stage WT tile [256][64] f16
      const int n = tid;
      const f16* src = Wm + n * 256 + kb * 64;
      const int sw = (n & 7) << 4;
#pragma unroll
      for (int j = 0; j < 8; ++j) {
        f16x8 v = *(const f16x8*)(src + j * 8);
        *(f16x8*)((char*)Wld + n * 128 + ((j * 16) ^ sw)) = v;
      }
    }
    __syncthreads();
#pragma unroll
    for (int kk = 0; kk < 2; ++kk) {
      const int arow = w * 16 + (lane & 15);
      const int ko = kk * 64 + (lane >> 4) * 16;
      f16x8 a = *(const f16x8*)((char*)Ald + arow * 128 + (ko ^ ((arow & 7) << 4)));
#pragma unroll
      for (int nt = 0; nt < 16; ++nt) {
        const int n = nt * 16 + (lane & 15);
        f16x8 b = *(const f16x8*)((char*)Wld + n * 128 + (ko ^ ((n & 7) << 4)));
        acc[nt] = mfma16(a, b, acc[nt]);
      }
    }
  }
  const int rl = (lane >> 4) * 4;
#pragma unroll
  for (int nt = 0; nt < 16; ++nt) {
    const int col = nt * 16 + (lane & 15);
#pragma unroll
    for (int j = 0; j < 4; ++j)
      O[(size_t)(row0 + w * 16 + rl + j) * ND + col] = (f16)acc[nt][j];
  }
}

// ---------------- K1c: VT[b][d][key] = Vh[b][key][d] (LDS-tiled transpose)
__global__ __launch_bounds__(256) void k1c_vt(const f16* __restrict__ Vh,
                                              f16* __restrict__ VT) {
  const int b = blockIdx.z;
  const int k0 = blockIdx.x * 64;
  const int d0 = blockIdx.y * 64;
  __shared__ f16 T[64][72];  // pad 8 f16
  const int tid = threadIdx.x;
  const f16* Vb = Vh + (size_t)b * NL * ND;
  {
    const int r = tid >> 2, c = (tid & 3) * 16;
    f16x8 a = *(const f16x8*)(Vb + (size_t)(k0 + r) * ND + d0 + c);
    f16x8 bq = *(const f16x8*)(Vb + (size_t)(k0 + r) * ND + d0 + c + 8);
    *(f16x8*)&T[r][c] = a;
    *(f16x8*)&T[r][c + 8] = bq;
  }
  __syncthreads();
  {
    const int d = tid >> 2, c = (tid & 3) * 16;
    f16 tmp[16];
#pragma unroll
    for (int j = 0; j < 16; ++j) tmp[j] = T[c + j][d];
    f16* dst = VT + (size_t)b * ND * NL + (size_t)(d0 + d) * NL + k0 + c;
    *(f16x8*)dst = *(f16x8*)&tmp[0];
    *(f16x8*)(dst + 8) = *(f16x8*)&tmp[8];
  }
}

// ---------------- K2: QE[b] = Q[b] @ (K[b]-Q[b])^T (r12 proven form).
__global__ __launch_bounds__(256) void k2_qe(const f16* __restrict__ Qh,
                                             const f16* __restrict__ Kh,
                                             f16* __restrict__ QEh) {
  const int b = blockIdx.z;
  const int m0 = blockIdx.x * 128, n0 = blockIdx.y * 128;
  const int tid = threadIdx.x, lane = tid & 63, w = tid >> 6;
  const int wr = (w >> 1) * 64, wc = (w & 1) * 64;
  const f16* Qb = Qh + (size_t)b * NL * ND;
  const f16* Kb = Kh + (size_t)b * NL * ND;

  __shared__ f16 As[128 * 64];
  __shared__ f16 Bs[128 * 64];

  f32x4 acc[4][4];
#pragma unroll
  for (int i = 0; i < 4; ++i)
#pragma unroll
    for (int j = 0; j < 4; ++j) acc[i][j] = f32x4{0.f, 0.f, 0.f, 0.f};

  for (int kb = 0; kb < 4; ++kb) {
    __syncthreads();
#pragma unroll
    for (int j = 0; j < 4; ++j) {
      const int c = j * 256 + tid;
      const int r = c >> 3;
      const int ko = (c & 7) * 16;
      const int sw = (r & 7) << 4;
      f16x8 va = *(const f16x8*)((const char*)(Qb + (size_t)(m0 + r) * ND + kb * 64) + ko);
      *(f16x8*)((char*)As + r * 128 + (ko ^ sw)) = va;
      f16x8 vk = *(const f16x8*)((const char*)(Kb + (size_t)(n0 + r) * ND + kb * 64) + ko);
      f16x8 vq = *(const f16x8*)((const char*)(Qb + (size_t)(n0 + r) * ND + kb * 64) + ko);
      *(f16x8*)((char*)Bs + r * 128 + (ko ^ sw)) = vk - vq;  // E = K - Q
    }
    __syncthreads();
#pragma unroll
    for (int kk = 0; kk < 2; ++kk) {
      const int ko = kk * 64 + (lane >> 4) * 16;
      f16x8 a[4], bf[4];
#pragma unroll
      for (int mt = 0; mt < 4; ++mt) {
        const int r = wr + mt * 16 + (lane & 15);
        a[mt] = *(const f16x8*)((char*)As + r * 128 + (ko ^ ((r & 7) << 4)));
      }
#pragma unroll
      for (int nt = 0; nt < 4; ++nt) {
        const int r = wc + nt * 16 + (lane & 15);
        bf[nt] = *(const f16x8*)((char*)Bs + r * 128 + (ko ^ ((r & 7) << 4)));
      }
#pragma unroll
      for (int mt = 0; mt < 4; ++mt)
#pragma unroll
        for (int nt = 0; nt < 4; ++nt) acc[mt][nt] = mfma16(a[mt], bf[nt], acc[mt][nt]);
    }
  }
  f16* outb = QEh + (size_t)b * NL * NL;
#pragma unroll
  for (int mt = 0; mt < 4; ++mt)
#pragma unroll
    for (int nt = 0; nt < 4; ++nt) {
      const int col = n0 + wc + nt * 16 + (lane & 15);
#pragma unroll
      for (int j = 0; j < 4; ++j) {
        const int row = m0 + wr + mt * 16 + (lane >> 4) * 4 + j;
        outb[(size_t)row * NL + col] = (f16)acc[mt][nt][j];
      }
    }
}

// ---------------- K3p v2: d-split flash attention partials.
// Wave w: QK^T+softmax for q rows [qw,qw+16); PV for d-slice [64w,64w+64)
// over ALL 64 q rows. P shared via LDS in FRAG-ORDER (base+lane*8 both
// sides -> conflict-free). V from pre-transposed VT as contiguous f16x4
// global loads (no V LDS at all). K double-buffered via global_load_lds
// (pre-swizzled source) -> ONE barrier per iteration.
#define NITP 16
__global__ __launch_bounds__(256, 2) void k3_part(
    const f16* __restrict__ Qh, const f16* __restrict__ Kh, const f16* __restrict__ VT,
    const f16* __restrict__ QEh, f16* __restrict__ Pac, float* __restrict__ Pml) {
  __shared__ char Kld[2][16384];   // [32][256] f16, swizzled ((key&7)<<4)
  __shared__ char Pfr[2][4096];    // frag-order: (w*2+nt)*512 + lane*8
  __shared__ float alf[2][64];
  __shared__ int rfl[2][4];
  __shared__ float mlinv[64];

  const int b = blockIdx.y, g = blockIdx.z, q0 = blockIdx.x * 64;
  const int tid = threadIdx.x, lane = tid & 63, w = tid >> 6, gi = lane >> 4;
  const int qw = q0 + w * 16;
  const int dbase = w * 64;

  const f16* Qb = Qh + (size_t)b * NL * ND;
  const f16* Kb = Kh + (size_t)b * NL * ND;
  const f16* VTb = VT + (size_t)b * ND * NL;
  const f16* QEb = QEh + (size_t)b * NL * NL;

  const int qa = qw + (lane & 15);
  f16x8 qf[8];
#pragma unroll
  for (int kk = 0; kk < 8; ++kk)
    qf[kk] = *(const f16x8*)(Qb + (size_t)qa * ND + kk * 32 + gi * 8);

  f32x4 acc[4][4];  // [qt][dt]; q = qt*16+4*gi+j, d = dbase+dt*16+(lane&15)
#pragma unroll
  for (int i = 0; i < 4; ++i)
#pragma unroll
    for (int j = 0; j < 4; ++j) acc[i][j] = f32x4{0.f, 0.f, 0.f, 0.f};
  float mrun = -1e30f, lrun = 0.f;

  auto kstage = [&](int t, int buf) {
    const char* src = (const char*)(Kb + (size_t)(g * NITP + t) * 32 * ND);
#pragma unroll
    for (int i = 0; i < 4; ++i) {
      const int chunk = w * 4 + i;              // wave-uniform
      const int r = chunk * 2 + (lane >> 5);    // key row (512B rows)
      const int co = ((lane & 31) * 16) ^ ((r & 7) << 4);
      gl_lds16(src + r * 512 + co, Kld[buf] + chunk * 1024);
    }
  };

  kstage(0, 0);
  __syncthreads();

  for (int t = 0; t < NITP; ++t) {
    const int pb = t & 1;
    const int k0 = (g * NITP + t) * 32;

    // srel gather (8 scalar, L3-resident QE)
    float srel[2][4];
#pragma unroll
    for (int nt = 0; nt < 2; ++nt)
#pragma unroll
      for (int j = 0; j < 4; ++j) {
        const int k = k0 + nt * 16 + gi * 4 + j;
        const int dq = k - qa;
        const size_t a1 = (size_t)qa * NL + (size_t)(NL - 1 + dq);
        const size_t a2 = (size_t)(qa + 1) * NL + (size_t)(dq - 2);
        const float v = (float)QEb[(dq <= 0) ? a1 : a2];
        srel[nt][j] = (dq == 1) ? 0.f : v;
      }

    if (t < NITP - 1) kstage(t + 1, pb ^ 1);  // async into other buffer

    // QK^T from Kld[pb]
    f32x4 s[2] = {f32x4{0.f, 0.f, 0.f, 0.f}, f32x4{0.f, 0.f, 0.f, 0.f}};
#pragma unroll
    for (int kk = 0; kk < 8; ++kk) {
      const int ko = kk * 64 + gi * 16;
#pragma unroll
      for (int nt = 0; nt < 2; ++nt) {
        const int key = nt * 16 + (lane & 15);
        f16x8 af = *(const f16x8*)(Kld[pb] + key * 512 + (ko ^ ((key & 7) << 4)));
        s[nt] = mfma16(af, qf[kk], s[nt]);
      }
    }

    float sv[2][4];
#pragma unroll
    for (int nt = 0; nt < 2; ++nt)
#pragma unroll
      for (int j = 0; j < 4; ++j) sv[nt][j] = 0.0625f * (s[nt][j] + srel[nt][j]);

    float pm = fmaxf(fmaxf(fmaxf(sv[0][0], sv[0][1]), fmaxf(sv[0][2], sv[0][3])),
                     fmaxf(fmaxf(sv[1][0], sv[1][1]), fmaxf(sv[1][2], sv[1][3])));
    pm = fmaxf(pm, __shfl_xor(pm, 16, 64));
    pm = fmaxf(pm, __shfl_xor(pm, 32, 64));

    const int doresc = (int)__any(pm > mrun + 8.f);
    if (lane == 0) rfl[pb][w] = doresc;

    float p[2][4];
    float al = 1.f;
    if (doresc) {
      const float mn = fmaxf(mrun, pm);
      al = __expf(mrun - mn);
      mrun = mn;
    }
#pragma unroll
    for (int nt = 0; nt < 2; ++nt)
#pragma unroll
      for (int j = 0; j < 4; ++j) p[nt][j] = __expf(sv[nt][j] - mrun);
    float rs = (p[0][0] + p[0][1]) + (p[0][2] + p[0][3]) +
               (p[1][0] + p[1][1]) + (p[1][2] + p[1][3]);
    rs += __shfl_xor(rs, 16, 64);
    rs += __shfl_xor(rs, 32, 64);
    lrun = lrun * al + rs;
    if (gi == 0) alf[pb][w * 16 + (lane & 15)] = al;

    union {
      fp16x2 h2[2];
      f16x4 h4;
    } pu0, pu1;
    pu0.h2[0] = __builtin_amdgcn_cvt_pkrtz(p[0][0], p[0][1]);
    pu0.h2[1] = __builtin_amdgcn_cvt_pkrtz(p[0][2], p[0][3]);
    pu1.h2[0] = __builtin_amdgcn_cvt_pkrtz(p[1][0], p[1][1]);
    pu1.h2[1] = __builtin_amdgcn_cvt_pkrtz(p[1][2], p[1][3]);
    *(f16x4*)(Pfr[pb] + (w * 2 + 0) * 512 + lane * 8) = pu0.h4;
    *(f16x4*)(Pfr[pb] + (w * 2 + 1) * 512 + lane * 8) = pu1.h4;

    // V frags for this tile (issued just before barrier; drained by its vmcnt)
    f16x4 vf[4][2];
#pragma unroll
    for (int dt = 0; dt < 4; ++dt)
#pragma unroll
      for (int nt = 0; nt < 2; ++nt)
        vf[dt][nt] = *(const f16x4*)(VTb + (size_t)(dbase + dt * 16 + (lane & 15)) * NL +
                                     k0 + nt * 16 + 4 * gi);

    __syncthreads();

    if (rfl[pb][0] | rfl[pb][1] | rfl[pb][2] | rfl[pb][3]) {
#pragma unroll
      for (int qt = 0; qt < 4; ++qt)
#pragma unroll
        for (int j = 0; j < 4; ++j) {
          const float a = alf[pb][qt * 16 + 4 * gi + j];
#pragma unroll
          for (int dt = 0; dt < 4; ++dt) acc[qt][dt][j] *= a;
        }
    }

#pragma unroll
    for (int qt = 0; qt < 4; ++qt) {
      f16x4 pa0 = *(const f16x4*)(Pfr[pb] + (qt * 2 + 0) * 512 + lane * 8);
      f16x4 pa1 = *(const f16x4*)(Pfr[pb] + (qt * 2 + 1) * 512 + lane * 8);
#pragma unroll
      for (int dt = 0; dt < 4; ++dt) {
        acc[qt][dt] = __builtin_amdgcn_mfma_f32_16x16x16f16(pa0, vf[dt][0], acc[qt][dt], 0, 0, 0);
        acc[qt][dt] = __builtin_amdgcn_mfma_f32_16x16x16f16(pa1, vf[dt][1], acc[qt][dt], 0, 0, 0);
      }
    }
  }

  // ---- epilogue: share 1/l, write l-normalized f16 partials + (m,l) ----
  if (gi == 0) mlinv[w * 16 + (lane & 15)] = 1.f / lrun;
  if (lane < 16) {
    const size_t r = (size_t)g * (NB * NL) + (size_t)b * NL + qw + lane;
    Pml[r * 2 + 0] = mrun;
    Pml[r * 2 + 1] = lrun;
  }
  __syncthreads();
  f16* Pb = Pac + ((size_t)g * (NB * NL) + (size_t)b * NL + q0) * ND;
#pragma unroll
  for (int qt = 0; qt < 4; ++qt)
#pragma unroll
    for (int j = 0; j < 4; ++j) {
      const int row = qt * 16 + 4 * gi + j;
      const float iv = mlinv[row];
#pragma unroll
      for (int dt = 0; dt < 4; ++dt)
        Pb[(size_t)row * ND + dbase + dt * 16 + (lane & 15)] = (f16)(acc[qt][dt][j] * iv);
    }
}

// ---------------- K4: combine 4 key-group normalized partials -> output
__global__ __launch_bounds__(256) void k4_comb(const f16* __restrict__ Pac,
                                               const float* __restrict__ Pml,
                                               float* __restrict__ Out) {
  const int row = blockIdx.x * 4 + (threadIdx.x >> 6);
  const int lane = threadIdx.x & 63;
  float m[4], l[4];
#pragma unroll
  for (int gq = 0; gq < 4; ++gq) {
    const size_t r = (size_t)gq * (NB * NL) + row;
    m[gq] = Pml[r * 2 + 0];
    l[gq] = Pml[r * 2 + 1];
  }
  const float M = fmaxf(fmaxf(m[0], m[1]), fmaxf(m[2], m[3]));
  float wgt[4];
  float denom = 0.f;
#pragma unroll
  for (int gq = 0; gq < 4; ++gq) {
    wgt[gq] = l[gq] * __expf(m[gq] - M);
    denom += wgt[gq];
  }
  const float inv = 1.f / denom;
  const size_t base = (size_t)row * ND + lane * 4;
  float o[4] = {0.f, 0.f, 0.f, 0.f};
#pragma unroll
  for (int gq = 0; gq < 4; ++gq) {
    f16x4 p = *(const f16x4*)(Pac + (size_t)gq * (NB * NL) * ND + base);
    const float s = wgt[gq] * inv;
#pragma unroll
    for (int e = 0; e < 4; ++e) o[e] += (float)p[e] * s;
  }
  f32x4 ov = {o[0], o[1], o[2], o[3]};
  *(f32x4*)(Out + base) = ov;
}

// ---------------- K3 fallback (r6): in-block 2-way key split, for small ws.
#define KVBUF 36864
#define NIT 32
__global__ __launch_bounds__(512, 2) void k3_attn(
    const f16* __restrict__ Qh, const f16* __restrict__ Kh, const f16* __restrict__ Vh,
    const f16* __restrict__ QEh, float* __restrict__ Out) {
  extern __shared__ char smemd[];
  const int b = blockIdx.y;
  const int q0 = blockIdx.x * 64;
  const int tid = threadIdx.x, lane = tid & 63, w = tid >> 6;
  const int g = w >> 2, wq = w & 3;
  const int qw = q0 + wq * 16;
  const int lt = tid & 255;
  const int gi = lane >> 4;

  float* Cst = (float*)smemd;
  float* ml = (float*)(smemd + 65536);

  const f16* Qb = Qh + (size_t)b * NL * ND;
  const f16* Kb = Kh + (size_t)b * NL * ND;
  const f16* Vb = Vh + (size_t)b * NL * ND;
  const f16* QEb = QEh + (size_t)b * NL * NL;

  f16x8 qf[8];
  {
    const int r = qw + (lane & 15);
#pragma unroll
    for (int kk = 0; kk < 8; ++kk)
      qf[kk] = *(const f16x8*)(Qb + (size_t)r * ND + kk * 32 + gi * 8);
  }

  f32x4 acc[16];
#pragma unroll
  for (int i = 0; i < 16; ++i) acc[i] = f32x4{0.f, 0.f, 0.f, 0.f};
  float mrun = -1e30f, lrun = 0.f;

  f16x8 kst[4], vst[4];
  const int kp = lt & 15, dch = lt >> 4;

  auto stage_load = [&](int t) {
    const f16* Ks = Kb + (size_t)(g * NIT + t) * 32 * ND;
#pragma unroll
    for (int j = 0; j < 4; ++j) {
      const int c = j * 256 + lt;
      kst[j] = *(const f16x8*)(Ks + (c >> 5) * ND + (c & 31) * 8);
    }
    const f16* Vs = Vb + (size_t)(g * NIT + t) * 32 * ND;
    vst[0] = *(const f16x8*)(Vs + (2 * kp) * ND + dch * 16);
    vst[1] = *(const f16x8*)(Vs + (2 * kp) * ND + dch * 16 + 8);
    vst[2] = *(const f16x8*)(Vs + (2 * kp + 1) * ND + dch * 16);
    vst[3] = *(const f16x8*)(Vs + (2 * kp + 1) * ND + dch * 16 + 8);
  };
  auto stage_write = [&]() {
    char* Kld = smemd + g * KVBUF;
    char* Vld = Kld + 16384;
#pragma unroll
    for (int j = 0; j < 4; ++j) {
      const int c = j * 256 + lt;
      const int key = c >> 5, d0 = (c & 31) * 16;
      *(f16x8*)(Kld + key * 512 + (d0 ^ ((key & 7) << 4))) = kst[j];
    }
#pragma unroll
    for (int jj = 0; jj < 16; ++jj) {
      f16x2 pr;
      pr.x = (jj < 8) ? vst[0][jj & 7] : vst[1][jj & 7];
      pr.y = (jj < 8) ? vst[2][jj & 7] : vst[3][jj & 7];
      *(f16x2*)(Vld + (dch * 16 + jj) * 80 + kp * 4) = pr;
    }
  };

  stage_load(0);
  stage_write();
  __syncthreads();

  const int qa = qw + (lane & 15);

  for (int t = 0; t < NIT; ++t) {
    const int k0 = (g * NIT + t) * 32;

    float srel[2][4];
#pragma unroll
    for (int nt = 0; nt < 2; ++nt)
#pragma unroll
      for (int j = 0; j < 4; ++j) {
        const int k = k0 + nt * 16 + gi * 4 + j;
        const int dq = k - qa;
        const size_t a1 = (size_t)qa * NL + (size_t)(NL - 1 + dq);
        const size_t a2 = (size_t)(qa + 1) * NL + (size_t)(dq - 2);
        const float v = (float)QEb[(dq <= 0) ? a1 : a2];
        srel[nt][j] = (dq == 1) ? 0.f : v;
      }

    if (t < NIT - 1) stage_load(t + 1);

    const char* Kld = smemd + g * KVBUF;
    const char* Vld = Kld + 16384;

    f32x4 s[2] = {f32x4{0.f, 0.f, 0.f, 0.f}, f32x4{0.f, 0.f, 0.f, 0.f}};
#pragma unroll
    for (int kk = 0; kk < 8; ++kk) {
      const int ko = kk * 64 + gi * 16;
#pragma unroll
      for (int nt = 0; nt < 2; ++nt) {
        const int key = nt * 16 + (lane & 15);
        f16x8 af = *(const f16x8*)(Kld + key * 512 + (ko ^ ((key & 7) << 4)));
        s[nt] = mfma16(af, qf[kk], s[nt]);
      }
    }

    float sv[2][4];
#pragma unroll
    for (int nt = 0; nt < 2; ++nt)
#pragma unroll
      for (int j = 0; j < 4; ++j) sv[nt][j] = 0.0625f * (s[nt][j] + srel[nt][j]);

    float pm = fmaxf(fmaxf(fmaxf(sv[0][0], sv[0][1]), fmaxf(sv[0][2], sv[0][3])),
                     fmaxf(fmaxf(sv[1][0], sv[1][1]), fmaxf(sv[1][2], sv[1][3])));
    pm = fmaxf(pm, __shfl_xor(pm, 16, 64));
    pm = fmaxf(pm, __shfl_xor(pm, 32, 64));

    float p[2][4];
    if (__any(pm > mrun + 8.f)) {
      const float mn = fmaxf(mrun, pm);
      const float al = __expf(mrun - mn);
      mrun = mn;
#pragma unroll
      for (int nt = 0; nt < 2; ++nt)
#pragma unroll
        for (int j = 0; j < 4; ++j) p[nt][j] = __expf(sv[nt][j] - mrun);
      float rs = (p[0][0] + p[0][1]) + (p[0][2] + p[0][3]) +
                 (p[1][0] + p[1][1]) + (p[1][2] + p[1][3]);
      rs += __shfl_xor(rs, 16, 64);
      rs += __shfl_xor(rs, 32, 64);
      lrun = lrun * al + rs;
#pragma unroll
      for (int j = 0; j < 4; ++j) {
        const float aj = __shfl(al, gi * 4 + j, 16);
#pragma unroll
        for (int dt = 0; dt < 16; ++dt) acc[dt][j] *= aj;
      }
    } else {
#pragma unroll
      for (int nt = 0; nt < 2; ++nt)
#pragma unroll
        for (int j = 0; j < 4; ++j) p[nt][j] = __expf(sv[nt][j] - mrun);
      float rs = (p[0][0] + p[0][1]) + (p[0][2] + p[0][3]) +
                 (p[1][0] + p[1][1]) + (p[1][2] + p[1][3]);
      rs += __shfl_xor(rs, 16, 64);
      rs += __shfl_xor(rs, 32, 64);
      lrun += rs;
    }

    union {
      fp16x2 h2[2];
      f16x4 h4;
    } pu0, pu1;
    pu0.h2[0] = __builtin_amdgcn_cvt_pkrtz(p[0][0], p[0][1]);
    pu0.h2[1] = __builtin_amdgcn_cvt_pkrtz(p[0][2], p[0][3]);
    pu1.h2[0] = __builtin_amdgcn_cvt_pkrtz(p[1][0], p[1][1]);
    pu1.h2[1] = __builtin_amdgcn_cvt_pkrtz(p[1][2], p[1][3]);

#pragma unroll
    for (int dt = 0; dt < 16; ++dt) {
      const char* vrow = Vld + (dt * 16 + (lane & 15)) * 80 + 8 * gi;
      f16x4 v0 = *(const f16x4*)(vrow);
      f16x4 v1 = *(const f16x4*)(vrow + 32);
      acc[dt] = __builtin_amdgcn_mfma_f32_16x16x16f16(pu0.h4, v0, acc[dt], 0, 0, 0);
      acc[dt] = __builtin_amdgcn_mfma_f32_16x16x16f16(pu1.h4, v1, acc[dt], 0, 0, 0);
    }

    __syncthreads();
    if (t < NIT - 1) stage_write();
    __syncthreads();
  }

  if (g == 1) {
#pragma unroll
    for (int dt = 0; dt < 16; ++dt)
#pragma unroll
      for (int j = 0; j < 4; ++j)
        Cst[wq * 4096 + (gi * 4 + j) * 256 + dt * 16 + (lane & 15)] = acc[dt][j];
    if (lane < 16) {
      ml[(wq * 16 + lane) * 2 + 0] = mrun;
      ml[(wq * 16 + lane) * 2 + 1] = lrun;
    }
  }
  __syncthreads();
  if (g == 0) {
    float* Ob = Out + (size_t)b * NL * ND;
#pragma unroll
    for (int j = 0; j < 4; ++j) {
      const int rloc = gi * 4 + j;
      const float m0r = __shfl(mrun, rloc, 16);
      const float l0r = __shfl(lrun, rloc, 16);
      const float m1 = ml[(wq * 16 + rloc) * 2 + 0];
      const float l1 = ml[(wq * 16 + rloc) * 2 + 1];
      const float M = fmaxf(m0r, m1);
      const float c0 = __expf(m0r - M), c1 = __expf(m1 - M);
      const float inv = 1.f / (l0r * c0 + l1 * c1);
      const int row = qw + rloc;
#pragma unroll
      for (int dt = 0; dt < 16; ++dt) {
        const float o1 = Cst[wq * 4096 + rloc * 256 + dt * 16 + (lane & 15)];
        Ob[(size_t)row * ND + dt * 16 + (lane & 15)] = (acc[dt][j] * c0 + o1 * c1) * inv;
      }
    }
  }
}

extern "C" void kernel_launch(void* const* d_in, const int* in_sizes, int n_in,
                              void* d_out, int out_size, void* d_ws, size_t ws_size,
                              hipStream_t stream) {
  (void)in_sizes; (void)n_in; (void)out_size;
  const float* inQ = (const float*)d_in[0];
  const float* inK = (const float*)d_in[1];
  const float* inV = (const float*)d_in[2];
  const float* Wq = (const float*)d_in[3];
  const float* Wk = (const float*)d_in[4];
  const float* Wv = (const float*)d_in[5];
  float* out = (float*)d_out;

  // ws layout (f16): Qh,Kh,Vh [B*L*D]; WT; QEh [B*L*L]; Pac [4][B*L][D];
  // (f32) Pml [4][B*L][2]; (f16) VT [B][D][L].
  f16* ws = (f16*)d_ws;
  f16* Qh = ws;
  f16* Kh = Qh + (size_t)QKV_ELEMS;
  f16* Vh = Kh + (size_t)QKV_ELEMS;
  f16* WT = Vh + (size_t)QKV_ELEMS;
  f16* QEh = WT + 3 * 65536;
  f16* Pac = QEh + (size_t)NB * NL * NL;
  float* Pml = (float*)(Pac + (size_t)4 * QKV_ELEMS);
  f16* VT = (f16*)(Pml + 4 * NB * NL * 2);
  const size_t need = (size_t)((char*)(VT + (size_t)QKV_ELEMS) - (char*)d_ws);

  k0_wt<<<dim3(768), dim3(256), 0, stream>>>(Wq, Wk, Wv, WT);
  k1_proj<<<dim3(256, 3), dim3(256), 0, stream>>>(inQ, inK, inV, WT, Qh, Kh, Vh);
  k2_qe<<<dim3(16, 16, 8), dim3(256), 0, stream>>>(Qh, Kh, QEh);
  if (ws_size >= need) {
    k1c_vt<<<dim3(32, 4, 8), dim3(256), 0, stream>>>(Vh, VT);
    k3_part<<<dim3(32, 8, 4), dim3(256), 0, stream>>>(Qh, Kh, VT, QEh, Pac, Pml);
    k4_comb<<<dim3(NB * NL / 4), dim3(256), 0, stream>>>(Pac, Pml, out);
  } else {
    k3_attn<<<dim3(32, 8), dim3(512), 73728, stream>>>(Qh, Kh, Vh, QEh, out);
  }
}

// Round 15
// 189.864 us; speedup vs baseline: 1.0975x; 1.0975x over previous
//
#include <hip/hip_runtime.h>
#include <hip/hip_fp16.h>
#include <stdint.h>

typedef _Float16 f16;
typedef _Float16 f16x2 __attribute__((ext_vector_type(2)));
typedef _Float16 f16x4 __attribute__((ext_vector_type(4)));
typedef _Float16 f16x8 __attribute__((ext_vector_type(8)));
typedef __fp16 fp16x2 __attribute__((ext_vector_type(2)));  // cvt_pkrtz return type
typedef float f32x4 __attribute__((ext_vector_type(4)));

#define NB 8
#define NL 2048
#define ND 256
#define QKV_ELEMS (NB * NL * ND)   // 4194304

__device__ __forceinline__ f32x4 mfma16(f16x8 a, f16x8 b, f32x4 c) {
  return __builtin_amdgcn_mfma_f32_16x16x32_f16(a, b, c, 0, 0, 0);
}

// ---------------- K0: transpose+convert weights: WT[m][n][k] = (f16)W_m[k][n]
__global__ void k0_wt(const float* __restrict__ Wq, const float* __restrict__ Wk,
                      const float* __restrict__ Wv, f16* __restrict__ WT) {
  int id = blockIdx.x * 256 + threadIdx.x;  // 0..196607
  int m = id >> 16;
  int r = id & 65535;
  int k = r >> 8, n = r & 255;
  const float* W = (m == 0) ? Wq : (m == 1) ? Wk : Wv;
  WT[m * 65536 + n * 256 + k] = (f16)W[k * 256 + n];
}

// ---------------- K1: projections (fp32 A, f16 MFMA, f16 out). 64 rows/block.
__global__ __launch_bounds__(256) void k1_proj(
    const float* __restrict__ Aq, const float* __restrict__ Ak, const float* __restrict__ Av,
    const f16* __restrict__ WT, f16* __restrict__ Qh, f16* __restrict__ Kh,
    f16* __restrict__ Vh) {
  const int m = blockIdx.y;
  const float* A = (m == 0) ? Aq : (m == 1) ? Ak : Av;
  f16* O = (m == 0) ? Qh : (m == 1) ? Kh : Vh;
  const f16* Wm = WT + m * 65536;
  const int row0 = blockIdx.x * 64;
  const int tid = threadIdx.x;
  const int lane = tid & 63, w = tid >> 6;

  __shared__ f16 Ald[64 * 64];    // [r][k], swizzled ((r&7)<<4) on byte offset
  __shared__ f16 Wld[256 * 64];   // [n][k], swizzled ((n&7)<<4)

  f32x4 acc[16];
#pragma unroll
  for (int i = 0; i < 16; ++i) acc[i] = f32x4{0.f, 0.f, 0.f, 0.f};

  for (int kb = 0; kb < 4; ++kb) {
    __syncthreads();
    {  // stage A tile 64x64 fp32 -> f16
      const int r = tid >> 2, c0 = (tid & 3) * 16;
      const float* src = A + (size_t)(row0 + r) * ND + kb * 64 + c0;
      f16x8 h0, h1;
#pragma unroll
      for (int j = 0; j < 8; ++j) h0[j] = (f16)src[j];
#pragma unroll
      for (int j = 0; j < 8; ++j) h1[j] = (f16)src[8 + j];
      const int sw = (r & 7) << 4;
      *(f16x8*)((char*)Ald + r * 128 + ((c0 * 2) ^ sw)) = h0;
      *(f16x8*)((char*)Ald + r * 128 + ((c0 * 2 + 16) ^ sw)) = h1;
    }
    {  // stage WT tile [256][64] f16
      const int n = tid;
      const f16* src = Wm + n * 256 + kb * 64;
      const int sw = (n & 7) << 4;
#pragma unroll
      for (int j = 0; j < 8; ++j) {
        f16x8 v = *(const f16x8*)(src + j * 8);
        *(f16x8*)((char*)Wld + n * 128 + ((j * 16) ^ sw)) = v;
      }
    }
    __syncthreads();
#pragma unroll
    for (int kk = 0; kk < 2; ++kk) {
      const int arow = w * 16 + (lane & 15);
      const int ko = kk * 64 + (lane >> 4) * 16;
      f16x8 a = *(const f16x8*)((char*)Ald + arow * 128 + (ko ^ ((arow & 7) << 4)));
#pragma unroll
      for (int nt = 0; nt < 16; ++nt) {
        const int n = nt * 16 + (lane & 15);
        f16x8 b = *(const f16x8*)((char*)Wld + n * 128 + (ko ^ ((n & 7) << 4)));
        acc[nt] = mfma16(a, b, acc[nt]);
      }
    }
  }
  const int rl = (lane >> 4) * 4;
#pragma unroll
  for (int nt = 0; nt < 16; ++nt) {
    const int col = nt * 16 + (lane & 15);
#pragma unroll
    for (int j = 0; j < 4; ++j)
      O[(size_t)(row0 + w * 16 + rl + j) * ND + col] = (f16)acc[nt][j];
  }
}

// ---------------- K2: QE[b] = Q[b] @ (K[b]-Q[b])^T, 128x128 tile, f16 out.
// E = K - Q computed on the fly during B-tile staging.
__global__ __launch_bounds__(256) void k2_qe(const f16* __restrict__ Qh,
                                             const f16* __restrict__ Kh,
                                             f16* __restrict__ QEh) {
  const int b = blockIdx.z;
  const int m0 = blockIdx.x * 128, n0 = blockIdx.y * 128;
  const int tid = threadIdx.x, lane = tid & 63, w = tid >> 6;
  const int wr = (w >> 1) * 64, wc = (w & 1) * 64;
  const f16* Qb = Qh + (size_t)b * NL * ND;
  const f16* Kb = Kh + (size_t)b * NL * ND;

  __shared__ f16 As[128 * 64];  // [r][k] swizzled ((r&7)<<4)
  __shared__ f16 Bs[128 * 64];

  f32x4 acc[4][4];
#pragma unroll
  for (int i = 0; i < 4; ++i)
#pragma unroll
    for (int j = 0; j < 4; ++j) acc[i][j] = f32x4{0.f, 0.f, 0.f, 0.f};

  for (int kb = 0; kb < 4; ++kb) {
    __syncthreads();
#pragma unroll
    for (int j = 0; j < 4; ++j) {
      const int c = j * 256 + tid;       // 1024 chunks of 16B
      const int r = c >> 3;
      const int ko = (c & 7) * 16;       // byte offset in row
      const int sw = (r & 7) << 4;
      f16x8 va = *(const f16x8*)((const char*)(Qb + (size_t)(m0 + r) * ND + kb * 64) + ko);
      *(f16x8*)((char*)As + r * 128 + (ko ^ sw)) = va;
      f16x8 vk = *(const f16x8*)((const char*)(Kb + (size_t)(n0 + r) * ND + kb * 64) + ko);
      f16x8 vq = *(const f16x8*)((const char*)(Qb + (size_t)(n0 + r) * ND + kb * 64) + ko);
      *(f16x8*)((char*)Bs + r * 128 + (ko ^ sw)) = vk - vq;  // E = K - Q
    }
    __syncthreads();
#pragma unroll
    for (int kk = 0; kk < 2; ++kk) {
      const int ko = kk * 64 + (lane >> 4) * 16;
      f16x8 a[4], bf[4];
#pragma unroll
      for (int mt = 0; mt < 4; ++mt) {
        const int r = wr + mt * 16 + (lane & 15);
        a[mt] = *(const f16x8*)((char*)As + r * 128 + (ko ^ ((r & 7) << 4)));
      }
#pragma unroll
      for (int nt = 0; nt < 4; ++nt) {
        const int r = wc + nt * 16 + (lane & 15);
        bf[nt] = *(const f16x8*)((char*)Bs + r * 128 + (ko ^ ((r & 7) << 4)));
      }
#pragma unroll
      for (int mt = 0; mt < 4; ++mt)
#pragma unroll
        for (int nt = 0; nt < 4; ++nt) acc[mt][nt] = mfma16(a[mt], bf[nt], acc[mt][nt]);
    }
  }
  f16* outb = QEh + (size_t)b * NL * NL;
#pragma unroll
  for (int mt = 0; mt < 4; ++mt)
#pragma unroll
    for (int nt = 0; nt < 4; ++nt) {
      const int col = n0 + wc + nt * 16 + (lane & 15);
#pragma unroll
      for (int j = 0; j < 4; ++j) {
        const int row = m0 + wr + mt * 16 + (lane >> 4) * 4 + j;
        outb[(size_t)row * NL + col] = (f16)acc[mt][nt][j];
      }
    }
}

// ---------------- K3p: 4-way key-split flash attention partials (r12 optimum).
// Grid (32 qtiles, 8 batch, 4 key-groups); 256 threads = 4 waves, NIT=16.
// launch_bounds(256,2) = measured optimum (VGPR 128, no spill).
// Measured-null/negative levers NOT used: setprio (r10 -16%), V-stride pad
// (r11 -2.6x, alignment), d-split+1-barrier (r14 -10%), gl_lds K staging
// (null), srel-first already folded in (r12, neutral-safe).
#define KVBUF 36864   // 16384 (K [32][256] swz) + 20480 (V [256][40])
#define NITP 16
__global__ __launch_bounds__(256, 2) void k3_part(
    const f16* __restrict__ Qh, const f16* __restrict__ Kh, const f16* __restrict__ Vh,
    const f16* __restrict__ QEh, f16* __restrict__ Pac, float* __restrict__ Pml) {
  __shared__ char smem[KVBUF];
  const int b = blockIdx.y;
  const int g = blockIdx.z;
  const int q0 = blockIdx.x * 64;
  const int tid = threadIdx.x, lane = tid & 63, w = tid >> 6;
  const int qw = q0 + w * 16;
  const int gi = lane >> 4;

  const f16* Qb = Qh + (size_t)b * NL * ND;
  const f16* Kb = Kh + (size_t)b * NL * ND;
  const f16* Vb = Vh + (size_t)b * NL * ND;
  const f16* QEb = QEh + (size_t)b * NL * NL;

  f16x8 qf[8];
  {
    const int r = qw + (lane & 15);
#pragma unroll
    for (int kk = 0; kk < 8; ++kk)
      qf[kk] = *(const f16x8*)(Qb + (size_t)r * ND + kk * 32 + gi * 8);
  }

  f32x4 acc[16];
#pragma unroll
  for (int i = 0; i < 16; ++i) acc[i] = f32x4{0.f, 0.f, 0.f, 0.f};
  float mrun = -1e30f, lrun = 0.f;

  f16x8 kst[4], vst[4];
  const int kp = tid & 15, dch = tid >> 4;

  auto stage_load = [&](int t) {
    const f16* Ks = Kb + (size_t)(g * NITP + t) * 32 * ND;
#pragma unroll
    for (int j = 0; j < 4; ++j) {
      const int c = j * 256 + tid;
      kst[j] = *(const f16x8*)(Ks + (c >> 5) * ND + (c & 31) * 8);
    }
    const f16* Vs = Vb + (size_t)(g * NITP + t) * 32 * ND;
    vst[0] = *(const f16x8*)(Vs + (2 * kp) * ND + dch * 16);
    vst[1] = *(const f16x8*)(Vs + (2 * kp) * ND + dch * 16 + 8);
    vst[2] = *(const f16x8*)(Vs + (2 * kp + 1) * ND + dch * 16);
    vst[3] = *(const f16x8*)(Vs + (2 * kp + 1) * ND + dch * 16 + 8);
  };
  auto stage_write = [&]() {
    char* Kld = smem;
    char* Vld = smem + 16384;
#pragma unroll
    for (int j = 0; j < 4; ++j) {
      const int c = j * 256 + tid;
      const int key = c >> 5, d0 = (c & 31) * 16;
      *(f16x8*)(Kld + key * 512 + (d0 ^ ((key & 7) << 4))) = kst[j];
    }
#pragma unroll
    for (int jj = 0; jj < 16; ++jj) {
      f16x2 pr;
      pr.x = (jj < 8) ? vst[0][jj & 7] : vst[1][jj & 7];  // key 2*kp
      pr.y = (jj < 8) ? vst[2][jj & 7] : vst[3][jj & 7];  // key 2*kp+1
      *(f16x2*)(Vld + (dch * 16 + jj) * 80 + kp * 4) = pr;
    }
  };

  stage_load(0);
  stage_write();
  __syncthreads();

  const int qa = qw + (lane & 15);

  for (int t = 0; t < NITP; ++t) {
    const int k0 = (g * NITP + t) * 32;

    // srel gather first (oldest in vmcnt FIFO)
    float srel[2][4];
#pragma unroll
    for (int nt = 0; nt < 2; ++nt)
#pragma unroll
      for (int j = 0; j < 4; ++j) {
        const int k = k0 + nt * 16 + gi * 4 + j;
        const int dq = k - qa;
        const size_t a1 = (size_t)qa * NL + (size_t)(NL - 1 + dq);
        const size_t a2 = (size_t)(qa + 1) * NL + (size_t)(dq - 2);
        const float v = (float)QEb[(dq <= 0) ? a1 : a2];
        srel[nt][j] = (dq == 1) ? 0.f : v;
      }

    if (t < NITP - 1) stage_load(t + 1);

    const char* Kld = smem;
    const char* Vld = smem + 16384;

    f32x4 s[2] = {f32x4{0.f, 0.f, 0.f, 0.f}, f32x4{0.f, 0.f, 0.f, 0.f}};
#pragma unroll
    for (int kk = 0; kk < 8; ++kk) {
      const int ko = kk * 64 + gi * 16;
#pragma unroll
      for (int nt = 0; nt < 2; ++nt) {
        const int key = nt * 16 + (lane & 15);
        f16x8 af = *(const f16x8*)(Kld + key * 512 + (ko ^ ((key & 7) << 4)));
        s[nt] = mfma16(af, qf[kk], s[nt]);
      }
    }

    float sv[2][4];
#pragma unroll
    for (int nt = 0; nt < 2; ++nt)
#pragma unroll
      for (int j = 0; j < 4; ++j) sv[nt][j] = 0.0625f * (s[nt][j] + srel[nt][j]);

    float pm = fmaxf(fmaxf(fmaxf(sv[0][0], sv[0][1]), fmaxf(sv[0][2], sv[0][3])),
                     fmaxf(fmaxf(sv[1][0], sv[1][1]), fmaxf(sv[1][2], sv[1][3])));
    pm = fmaxf(pm, __shfl_xor(pm, 16, 64));
    pm = fmaxf(pm, __shfl_xor(pm, 32, 64));

    float p[2][4];
    if (__any(pm > mrun + 8.f)) {
      const float mn = fmaxf(mrun, pm);
      const float al = __expf(mrun - mn);
      mrun = mn;
#pragma unroll
      for (int nt = 0; nt < 2; ++nt)
#pragma unroll
        for (int j = 0; j < 4; ++j) p[nt][j] = __expf(sv[nt][j] - mrun);
      float rs = (p[0][0] + p[0][1]) + (p[0][2] + p[0][3]) +
                 (p[1][0] + p[1][1]) + (p[1][2] + p[1][3]);
      rs += __shfl_xor(rs, 16, 64);
      rs += __shfl_xor(rs, 32, 64);
      lrun = lrun * al + rs;
#pragma unroll
      for (int j = 0; j < 4; ++j) {
        const float aj = __shfl(al, gi * 4 + j, 16);
#pragma unroll
        for (int dt = 0; dt < 16; ++dt) acc[dt][j] *= aj;
      }
    } else {
#pragma unroll
      for (int nt = 0; nt < 2; ++nt)
#pragma unroll
        for (int j = 0; j < 4; ++j) p[nt][j] = __expf(sv[nt][j] - mrun);
      float rs = (p[0][0] + p[0][1]) + (p[0][2] + p[0][3]) +
                 (p[1][0] + p[1][1]) + (p[1][2] + p[1][3]);
      rs += __shfl_xor(rs, 16, 64);
      rs += __shfl_xor(rs, 32, 64);
      lrun += rs;
    }

    union {
      fp16x2 h2[2];
      f16x4 h4;
    } pu0, pu1;
    pu0.h2[0] = __builtin_amdgcn_cvt_pkrtz(p[0][0], p[0][1]);
    pu0.h2[1] = __builtin_amdgcn_cvt_pkrtz(p[0][2], p[0][3]);
    pu1.h2[0] = __builtin_amdgcn_cvt_pkrtz(p[1][0], p[1][1]);
    pu1.h2[1] = __builtin_amdgcn_cvt_pkrtz(p[1][2], p[1][3]);

#pragma unroll
    for (int dt = 0; dt < 16; ++dt) {
      const char* vrow = Vld + (dt * 16 + (lane & 15)) * 80 + 8 * gi;
      f16x4 v0 = *(const f16x4*)(vrow);
      f16x4 v1 = *(const f16x4*)(vrow + 32);
      acc[dt] = __builtin_amdgcn_mfma_f32_16x16x16f16(pu0.h4, v0, acc[dt], 0, 0, 0);
      acc[dt] = __builtin_amdgcn_mfma_f32_16x16x16f16(pu1.h4, v1, acc[dt], 0, 0, 0);
    }

    __syncthreads();
    if (t < NITP - 1) stage_write();
    __syncthreads();
  }

  // ---- write l-normalized partials (f16) ----
  const float inv = 1.f / lrun;
  f16* Pb = Pac + ((size_t)g * (NB * NL) + (size_t)b * NL) * ND;
#pragma unroll
  for (int j = 0; j < 4; ++j) {
    const float invj = __shfl(inv, gi * 4 + j, 16);
    const int row = qw + gi * 4 + j;
#pragma unroll
    for (int dt = 0; dt < 16; ++dt)
      Pb[(size_t)row * ND + dt * 16 + (lane & 15)] = (f16)(acc[dt][j] * invj);
  }
  if (lane < 16) {
    const size_t r = (size_t)g * (NB * NL) + (size_t)b * NL + qw + lane;
    Pml[r * 2 + 0] = mrun;
    Pml[r * 2 + 1] = lrun;
  }
}

// ---------------- K4: combine 4 key-group normalized partials -> output
__global__ __launch_bounds__(256) void k4_comb(const f16* __restrict__ Pac,
                                               const float* __restrict__ Pml,
                                               float* __restrict__ Out) {
  const int row = blockIdx.x * 4 + (threadIdx.x >> 6);
  const int lane = threadIdx.x & 63;
  float m[4], l[4];
#pragma unroll
  for (int gq = 0; gq < 4; ++gq) {
    const size_t r = (size_t)gq * (NB * NL) + row;
    m[gq] = Pml[r * 2 + 0];
    l[gq] = Pml[r * 2 + 1];
  }
  const float M = fmaxf(fmaxf(m[0], m[1]), fmaxf(m[2], m[3]));
  float wgt[4];
  float denom = 0.f;
#pragma unroll
  for (int gq = 0; gq < 4; ++gq) {
    wgt[gq] = l[gq] * __expf(m[gq] - M);
    denom += wgt[gq];
  }
  const float inv = 1.f / denom;
  const size_t base = (size_t)row * ND + lane * 4;
  float o[4] = {0.f, 0.f, 0.f, 0.f};
#pragma unroll
  for (int gq = 0; gq < 4; ++gq) {
    f16x4 p = *(const f16x4*)(Pac + (size_t)gq * (NB * NL) * ND + base);
    const float s = wgt[gq] * inv;
#pragma unroll
    for (int e = 0; e < 4; ++e) o[e] += (float)p[e] * s;
  }
  f32x4 ov = {o[0], o[1], o[2], o[3]};
  *(f32x4*)(Out + base) = ov;
}

// ---------------- K3 fallback (r6): in-block 2-way key split, for small ws.
#define NIT 32
__global__ __launch_bounds__(512, 2) void k3_attn(
    const f16* __restrict__ Qh, const f16* __restrict__ Kh, const f16* __restrict__ Vh,
    const f16* __restrict__ QEh, float* __restrict__ Out) {
  extern __shared__ char smemd[];  // 73728 B
  const int b = blockIdx.y;
  const int q0 = blockIdx.x * 64;
  const int tid = threadIdx.x, lane = tid & 63, w = tid >> 6;
  const int g = w >> 2, wq = w & 3;
  const int qw = q0 + wq * 16;
  const int lt = tid & 255;
  const int gi = lane >> 4;

  float* Cst = (float*)smemd;
  float* ml = (float*)(smemd + 65536);

  const f16* Qb = Qh + (size_t)b * NL * ND;
  const f16* Kb = Kh + (size_t)b * NL * ND;
  const f16* Vb = Vh + (size_t)b * NL * ND;
  const f16* QEb = QEh + (size_t)b * NL * NL;

  f16x8 qf[8];
  {
    const int r = qw + (lane & 15);
#pragma unroll
    for (int kk = 0; kk < 8; ++kk)
      qf[kk] = *(const f16x8*)(Qb + (size_t)r * ND + kk * 32 + gi * 8);
  }

  f32x4 acc[16];
#pragma unroll
  for (int i = 0; i < 16; ++i) acc[i] = f32x4{0.f, 0.f, 0.f, 0.f};
  float mrun = -1e30f, lrun = 0.f;

  f16x8 kst[4], vst[4];
  const int kp = lt & 15, dch = lt >> 4;

  auto stage_load = [&](int t) {
    const f16* Ks = Kb + (size_t)(g * NIT + t) * 32 * ND;
#pragma unroll
    for (int j = 0; j < 4; ++j) {
      const int c = j * 256 + lt;
      kst[j] = *(const f16x8*)(Ks + (c >> 5) * ND + (c & 31) * 8);
    }
    const f16* Vs = Vb + (size_t)(g * NIT + t) * 32 * ND;
    vst[0] = *(const f16x8*)(Vs + (2 * kp) * ND + dch * 16);
    vst[1] = *(const f16x8*)(Vs + (2 * kp) * ND + dch * 16 + 8);
    vst[2] = *(const f16x8*)(Vs + (2 * kp + 1) * ND + dch * 16);
    vst[3] = *(const f16x8*)(Vs + (2 * kp + 1) * ND + dch * 16 + 8);
  };
  auto stage_write = [&]() {
    char* Kld = smemd + g * KVBUF;
    char* Vld = Kld + 16384;
#pragma unroll
    for (int j = 0; j < 4; ++j) {
      const int c = j * 256 + lt;
      const int key = c >> 5, d0 = (c & 31) * 16;
      *(f16x8*)(Kld + key * 512 + (d0 ^ ((key & 7) << 4))) = kst[j];
    }
#pragma unroll
    for (int jj = 0; jj < 16; ++jj) {
      f16x2 pr;
      pr.x = (jj < 8) ? vst[0][jj & 7] : vst[1][jj & 7];
      pr.y = (jj < 8) ? vst[2][jj & 7] : vst[3][jj & 7];
      *(f16x2*)(Vld + (dch * 16 + jj) * 80 + kp * 4) = pr;
    }
  };

  stage_load(0);
  stage_write();
  __syncthreads();

  const int qa = qw + (lane & 15);

  for (int t = 0; t < NIT; ++t) {
    const int k0 = (g * NIT + t) * 32;

    float srel[2][4];
#pragma unroll
    for (int nt = 0; nt < 2; ++nt)
#pragma unroll
      for (int j = 0; j < 4; ++j) {
        const int k = k0 + nt * 16 + gi * 4 + j;
        const int dq = k - qa;
        const size_t a1 = (size_t)qa * NL + (size_t)(NL - 1 + dq);
        const size_t a2 = (size_t)(qa + 1) * NL + (size_t)(dq - 2);
        const float v = (float)QEb[(dq <= 0) ? a1 : a2];
        srel[nt][j] = (dq == 1) ? 0.f : v;
      }

    if (t < NIT - 1) stage_load(t + 1);

    const char* Kld = smemd + g * KVBUF;
    const char* Vld = Kld + 16384;

    f32x4 s[2] = {f32x4{0.f, 0.f, 0.f, 0.f}, f32x4{0.f, 0.f, 0.f, 0.f}};
#pragma unroll
    for (int kk = 0; kk < 8; ++kk) {
      const int ko = kk * 64 + gi * 16;
#pragma unroll
      for (int nt = 0; nt < 2; ++nt) {
        const int key = nt * 16 + (lane & 15);
        f16x8 af = *(const f16x8*)(Kld + key * 512 + (ko ^ ((key & 7) << 4)));
        s[nt] = mfma16(af, qf[kk], s[nt]);
      }
    }

    float sv[2][4];
#pragma unroll
    for (int nt = 0; nt < 2; ++nt)
#pragma unroll
      for (int j = 0; j < 4; ++j) sv[nt][j] = 0.0625f * (s[nt][j] + srel[nt][j]);

    float pm = fmaxf(fmaxf(fmaxf(sv[0][0], sv[0][1]), fmaxf(sv[0][2], sv[0][3])),
                     fmaxf(fmaxf(sv[1][0], sv[1][1]), fmaxf(sv[1][2], sv[1][3])));
    pm = fmaxf(pm, __shfl_xor(pm, 16, 64));
    pm = fmaxf(pm, __shfl_xor(pm, 32, 64));

    float p[2][4];
    if (__any(pm > mrun + 8.f)) {
      const float mn = fmaxf(mrun, pm);
      const float al = __expf(mrun - mn);
      mrun = mn;
#pragma unroll
      for (int nt = 0; nt < 2; ++nt)
#pragma unroll
        for (int j = 0; j < 4; ++j) p[nt][j] = __expf(sv[nt][j] - mrun);
      float rs = (p[0][0] + p[0][1]) + (p[0][2] + p[0][3]) +
                 (p[1][0] + p[1][1]) + (p[1][2] + p[1][3]);
      rs += __shfl_xor(rs, 16, 64);
      rs += __shfl_xor(rs, 32, 64);
      lrun = lrun * al + rs;
#pragma unroll
      for (int j = 0; j < 4; ++j) {
        const float aj = __shfl(al, gi * 4 + j, 16);
#pragma unroll
        for (int dt = 0; dt < 16; ++dt) acc[dt][j] *= aj;
      }
    } else {
#pragma unroll
      for (int nt = 0; nt < 2; ++nt)
#pragma unroll
        for (int j = 0; j < 4; ++j) p[nt][j] = __expf(sv[nt][j] - mrun);
      float rs = (p[0][0] + p[0][1]) + (p[0][2] + p[0][3]) +
                 (p[1][0] + p[1][1]) + (p[1][2] + p[1][3]);
      rs += __shfl_xor(rs, 16, 64);
      rs += __shfl_xor(rs, 32, 64);
      lrun += rs;
    }

    union {
      fp16x2 h2[2];
      f16x4 h4;
    } pu0, pu1;
    pu0.h2[0] = __builtin_amdgcn_cvt_pkrtz(p[0][0], p[0][1]);
    pu0.h2[1] = __builtin_amdgcn_cvt_pkrtz(p[0][2], p[0][3]);
    pu1.h2[0] = __builtin_amdgcn_cvt_pkrtz(p[1][0], p[1][1]);
    pu1.h2[1] = __builtin_amdgcn_cvt_pkrtz(p[1][2], p[1][3]);

#pragma unroll
    for (int dt = 0; dt < 16; ++dt) {
      const char* vrow = Vld + (dt * 16 + (lane & 15)) * 80 + 8 * gi;
      f16x4 v0 = *(const f16x4*)(vrow);
      f16x4 v1 = *(const f16x4*)(vrow + 32);
      acc[dt] = __builtin_amdgcn_mfma_f32_16x16x16f16(pu0.h4, v0, acc[dt], 0, 0, 0);
      acc[dt] = __builtin_amdgcn_mfma_f32_16x16x16f16(pu1.h4, v1, acc[dt], 0, 0, 0);
    }

    __syncthreads();
    if (t < NIT - 1) stage_write();
    __syncthreads();
  }

  if (g == 1) {
#pragma unroll
    for (int dt = 0; dt < 16; ++dt)
#pragma unroll
      for (int j = 0; j < 4; ++j)
        Cst[wq * 4096 + (gi * 4 + j) * 256 + dt * 16 + (lane & 15)] = acc[dt][j];
    if (lane < 16) {
      ml[(wq * 16 + lane) * 2 + 0] = mrun;
      ml[(wq * 16 + lane) * 2 + 1] = lrun;
    }
  }
  __syncthreads();
  if (g == 0) {
    float* Ob = Out + (size_t)b * NL * ND;
#pragma unroll
    for (int j = 0; j < 4; ++j) {
      const int rloc = gi * 4 + j;
      const float m0r = __shfl(mrun, rloc, 16);
      const float l0r = __shfl(lrun, rloc, 16);
      const float m1 = ml[(wq * 16 + rloc) * 2 + 0];
      const float l1 = ml[(wq * 16 + rloc) * 2 + 1];
      const float M = fmaxf(m0r, m1);
      const float c0 = __expf(m0r - M), c1 = __expf(m1 - M);
      const float inv = 1.f / (l0r * c0 + l1 * c1);
      const int row = qw + rloc;
#pragma unroll
      for (int dt = 0; dt < 16; ++dt) {
        const float o1 = Cst[wq * 4096 + rloc * 256 + dt * 16 + (lane & 15)];
        Ob[(size_t)row * ND + dt * 16 + (lane & 15)] = (acc[dt][j] * c0 + o1 * c1) * inv;
      }
    }
  }
}

extern "C" void kernel_launch(void* const* d_in, const int* in_sizes, int n_in,
                              void* d_out, int out_size, void* d_ws, size_t ws_size,
                              hipStream_t stream) {
  (void)in_sizes; (void)n_in; (void)out_size;
  const float* inQ = (const float*)d_in[0];
  const float* inK = (const float*)d_in[1];
  const float* inV = (const float*)d_in[2];
  const float* Wq = (const float*)d_in[3];
  const float* Wk = (const float*)d_in[4];
  const float* Wv = (const float*)d_in[5];
  float* out = (float*)d_out;

  // ws layout (f16): Qh,Kh,Vh [B*L*D]; WT [3*256*256]; QEh [B*L*L];
  // Pac f16 [4][B*L][D]; then (f32) Pml [4][B*L][2].
  f16* ws = (f16*)d_ws;
  f16* Qh = ws;
  f16* Kh = Qh + (size_t)QKV_ELEMS;
  f16* Vh = Kh + (size_t)QKV_ELEMS;
  f16* WT = Vh + (size_t)QKV_ELEMS;
  f16* QEh = WT + 3 * 65536;
  f16* Pac = QEh + (size_t)NB * NL * NL;
  float* Pml = (float*)(Pac + (size_t)4 * QKV_ELEMS);
  const size_t need = (size_t)((char*)(Pml + 4 * NB * NL * 2) - (char*)d_ws);

  k0_wt<<<dim3(768), dim3(256), 0, stream>>>(Wq, Wk, Wv, WT);
  k1_proj<<<dim3(256, 3), dim3(256), 0, stream>>>(inQ, inK, inV, WT, Qh, Kh, Vh);
  k2_qe<<<dim3(16, 16, 8), dim3(256), 0, stream>>>(Qh, Kh, QEh);
  if (ws_size >= need) {
    k3_part<<<dim3(32, 8, 4), dim3(256), 0, stream>>>(Qh, Kh, Vh, QEh, Pac, Pml);
    k4_comb<<<dim3(NB * NL / 4), dim3(256), 0, stream>>>(Pac, Pml, out);
  } else {
    k3_attn<<<dim3(32, 8), dim3(512), 73728, stream>>>(Qh, Kh, Vh, QEh, out);
  }
}

// Round 16
// 189.231 us; speedup vs baseline: 1.1012x; 1.0033x over previous
//
#include <hip/hip_runtime.h>
#include <hip/hip_fp16.h>
#include <stdint.h>

typedef _Float16 f16;
typedef _Float16 f16x2 __attribute__((ext_vector_type(2)));
typedef _Float16 f16x4 __attribute__((ext_vector_type(4)));
typedef _Float16 f16x8 __attribute__((ext_vector_type(8)));
typedef __fp16 fp16x2 __attribute__((ext_vector_type(2)));  // cvt_pkrtz return type
typedef float f32x4 __attribute__((ext_vector_type(4)));

#define NB 8
#define NL 2048
#define ND 256
#define QKV_ELEMS (NB * NL * ND)   // 4194304

__device__ __forceinline__ f32x4 mfma16(f16x8 a, f16x8 b, f32x4 c) {
  return __builtin_amdgcn_mfma_f32_16x16x32_f16(a, b, c, 0, 0, 0);
}

// ---------------- K0: transpose+convert weights: WT[m][n][k] = (f16)W_m[k][n]
__global__ void k0_wt(const float* __restrict__ Wq, const float* __restrict__ Wk,
                      const float* __restrict__ Wv, f16* __restrict__ WT) {
  int id = blockIdx.x * 256 + threadIdx.x;  // 0..196607
  int m = id >> 16;
  int r = id & 65535;
  int k = r >> 8, n = r & 255;
  const float* W = (m == 0) ? Wq : (m == 1) ? Wk : Wv;
  WT[m * 65536 + n * 256 + k] = (f16)W[k * 256 + n];
}

// ---------------- K1: projections (fp32 A, f16 MFMA, f16 out). 64 rows/block.
__global__ __launch_bounds__(256) void k1_proj(
    const float* __restrict__ Aq, const float* __restrict__ Ak, const float* __restrict__ Av,
    const f16* __restrict__ WT, f16* __restrict__ Qh, f16* __restrict__ Kh,
    f16* __restrict__ Vh) {
  const int m = blockIdx.y;
  const float* A = (m == 0) ? Aq : (m == 1) ? Ak : Av;
  f16* O = (m == 0) ? Qh : (m == 1) ? Kh : Vh;
  const f16* Wm = WT + m * 65536;
  const int row0 = blockIdx.x * 64;
  const int tid = threadIdx.x;
  const int lane = tid & 63, w = tid >> 6;

  __shared__ f16 Ald[64 * 64];    // [r][k], swizzled ((r&7)<<4) on byte offset
  __shared__ f16 Wld[256 * 64];   // [n][k], swizzled ((n&7)<<4)

  f32x4 acc[16];
#pragma unroll
  for (int i = 0; i < 16; ++i) acc[i] = f32x4{0.f, 0.f, 0.f, 0.f};

  for (int kb = 0; kb < 4; ++kb) {
    __syncthreads();
    {  // stage A tile 64x64 fp32 -> f16
      const int r = tid >> 2, c0 = (tid & 3) * 16;
      const float* src = A + (size_t)(row0 + r) * ND + kb * 64 + c0;
      f16x8 h0, h1;
#pragma unroll
      for (int j = 0; j < 8; ++j) h0[j] = (f16)src[j];
#pragma unroll
      for (int j = 0; j < 8; ++j) h1[j] = (f16)src[8 + j];
      const int sw = (r & 7) << 4;
      *(f16x8*)((char*)Ald + r * 128 + ((c0 * 2) ^ sw)) = h0;
      *(f16x8*)((char*)Ald + r * 128 + ((c0 * 2 + 16) ^ sw)) = h1;
    }
    {  // stage WT tile [256][64] f16
      const int n = tid;
      const f16* src = Wm + n * 256 + kb * 64;
      const int sw = (n & 7) << 4;
#pragma unroll
      for (int j = 0; j < 8; ++j) {
        f16x8 v = *(const f16x8*)(src + j * 8);
        *(f16x8*)((char*)Wld + n * 128 + ((j * 16) ^ sw)) = v;
      }
    }
    __syncthreads();
#pragma unroll
    for (int kk = 0; kk < 2; ++kk) {
      const int arow = w * 16 + (lane & 15);
      const int ko = kk * 64 + (lane >> 4) * 16;
      f16x8 a = *(const f16x8*)((char*)Ald + arow * 128 + (ko ^ ((arow & 7) << 4)));
#pragma unroll
      for (int nt = 0; nt < 16; ++nt) {
        const int n = nt * 16 + (lane & 15);
        f16x8 b = *(const f16x8*)((char*)Wld + n * 128 + (ko ^ ((n & 7) << 4)));
        acc[nt] = mfma16(a, b, acc[nt]);
      }
    }
  }
  const int rl = (lane >> 4) * 4;
#pragma unroll
  for (int nt = 0; nt < 16; ++nt) {
    const int col = nt * 16 + (lane & 15);
#pragma unroll
    for (int j = 0; j < 4; ++j)
      O[(size_t)(row0 + w * 16 + rl + j) * ND + col] = (f16)acc[nt][j];
  }
}

// ---------------- K2: QE[b] = Q[b] @ (K[b]-Q[b])^T, 128x128 tile, f16 out.
// E = K - Q computed on the fly during B-tile staging.
__global__ __launch_bounds__(256) void k2_qe(const f16* __restrict__ Qh,
                                             const f16* __restrict__ Kh,
                                             f16* __restrict__ QEh) {
  const int b = blockIdx.z;
  const int m0 = blockIdx.x * 128, n0 = blockIdx.y * 128;
  const int tid = threadIdx.x, lane = tid & 63, w = tid >> 6;
  const int wr = (w >> 1) * 64, wc = (w & 1) * 64;
  const f16* Qb = Qh + (size_t)b * NL * ND;
  const f16* Kb = Kh + (size_t)b * NL * ND;

  __shared__ f16 As[128 * 64];  // [r][k] swizzled ((r&7)<<4)
  __shared__ f16 Bs[128 * 64];

  f32x4 acc[4][4];
#pragma unroll
  for (int i = 0; i < 4; ++i)
#pragma unroll
    for (int j = 0; j < 4; ++j) acc[i][j] = f32x4{0.f, 0.f, 0.f, 0.f};

  for (int kb = 0; kb < 4; ++kb) {
    __syncthreads();
#pragma unroll
    for (int j = 0; j < 4; ++j) {
      const int c = j * 256 + tid;       // 1024 chunks of 16B
      const int r = c >> 3;
      const int ko = (c & 7) * 16;       // byte offset in row
      const int sw = (r & 7) << 4;
      f16x8 va = *(const f16x8*)((const char*)(Qb + (size_t)(m0 + r) * ND + kb * 64) + ko);
      *(f16x8*)((char*)As + r * 128 + (ko ^ sw)) = va;
      f16x8 vk = *(const f16x8*)((const char*)(Kb + (size_t)(n0 + r) * ND + kb * 64) + ko);
      f16x8 vq = *(const f16x8*)((const char*)(Qb + (size_t)(n0 + r) * ND + kb * 64) + ko);
      *(f16x8*)((char*)Bs + r * 128 + (ko ^ sw)) = vk - vq;  // E = K - Q
    }
    __syncthreads();
#pragma unroll
    for (int kk = 0; kk < 2; ++kk) {
      const int ko = kk * 64 + (lane >> 4) * 16;
      f16x8 a[4], bf[4];
#pragma unroll
      for (int mt = 0; mt < 4; ++mt) {
        const int r = wr + mt * 16 + (lane & 15);
        a[mt] = *(const f16x8*)((char*)As + r * 128 + (ko ^ ((r & 7) << 4)));
      }
#pragma unroll
      for (int nt = 0; nt < 4; ++nt) {
        const int r = wc + nt * 16 + (lane & 15);
        bf[nt] = *(const f16x8*)((char*)Bs + r * 128 + (ko ^ ((r & 7) << 4)));
      }
#pragma unroll
      for (int mt = 0; mt < 4; ++mt)
#pragma unroll
        for (int nt = 0; nt < 4; ++nt) acc[mt][nt] = mfma16(a[mt], bf[nt], acc[mt][nt]);
    }
  }
  f16* outb = QEh + (size_t)b * NL * NL;
#pragma unroll
  for (int mt = 0; mt < 4; ++mt)
#pragma unroll
    for (int nt = 0; nt < 4; ++nt) {
      const int col = n0 + wc + nt * 16 + (lane & 15);
#pragma unroll
      for (int j = 0; j < 4; ++j) {
        const int row = m0 + wr + mt * 16 + (lane >> 4) * 4 + j;
        outb[(size_t)row * NL + col] = (f16)acc[mt][nt][j];
      }
    }
}

// ---------------- K3p: 4-way key-split flash attention partials.
// r12 optimum + DOUBLE-BUFFERED K/V (2x36.9 KB dynamic LDS) -> ONE barrier
// per iteration. Residency unchanged: (256,2) wave cap already limits to
// 2 blocks/CU (8 waves), and 73.7 KB LDS also allows exactly 2 blocks/CU.
// r4<->r6 measured this delta at -6% on the 512-thread variant.
// Measured-null/negative levers NOT used: setprio (r10 -16%), V-stride pad
// (r11 -2.6x), d-split (r14 -10%), gl_lds K staging (null).
#define KVBUF 36864   // 16384 (K [32][256] swz) + 20480 (V [256][40])
#define NITP 16
__global__ __launch_bounds__(256, 2) void k3_part(
    const f16* __restrict__ Qh, const f16* __restrict__ Kh, const f16* __restrict__ Vh,
    const f16* __restrict__ QEh, f16* __restrict__ Pac, float* __restrict__ Pml) {
  extern __shared__ char smem[];  // 2 * KVBUF = 73728 B
  const int b = blockIdx.y;
  const int g = blockIdx.z;
  const int q0 = blockIdx.x * 64;
  const int tid = threadIdx.x, lane = tid & 63, w = tid >> 6;
  const int qw = q0 + w * 16;
  const int gi = lane >> 4;

  const f16* Qb = Qh + (size_t)b * NL * ND;
  const f16* Kb = Kh + (size_t)b * NL * ND;
  const f16* Vb = Vh + (size_t)b * NL * ND;
  const f16* QEb = QEh + (size_t)b * NL * NL;

  f16x8 qf[8];
  {
    const int r = qw + (lane & 15);
#pragma unroll
    for (int kk = 0; kk < 8; ++kk)
      qf[kk] = *(const f16x8*)(Qb + (size_t)r * ND + kk * 32 + gi * 8);
  }

  f32x4 acc[16];
#pragma unroll
  for (int i = 0; i < 16; ++i) acc[i] = f32x4{0.f, 0.f, 0.f, 0.f};
  float mrun = -1e30f, lrun = 0.f;

  f16x8 kst[4], vst[4];
  const int kp = tid & 15, dch = tid >> 4;

  auto stage_load = [&](int t) {
    const f16* Ks = Kb + (size_t)(g * NITP + t) * 32 * ND;
#pragma unroll
    for (int j = 0; j < 4; ++j) {
      const int c = j * 256 + tid;
      kst[j] = *(const f16x8*)(Ks + (c >> 5) * ND + (c & 31) * 8);
    }
    const f16* Vs = Vb + (size_t)(g * NITP + t) * 32 * ND;
    vst[0] = *(const f16x8*)(Vs + (2 * kp) * ND + dch * 16);
    vst[1] = *(const f16x8*)(Vs + (2 * kp) * ND + dch * 16 + 8);
    vst[2] = *(const f16x8*)(Vs + (2 * kp + 1) * ND + dch * 16);
    vst[3] = *(const f16x8*)(Vs + (2 * kp + 1) * ND + dch * 16 + 8);
  };
  auto stage_write = [&](int buf) {
    char* Kld = smem + buf * KVBUF;
    char* Vld = Kld + 16384;
#pragma unroll
    for (int j = 0; j < 4; ++j) {
      const int c = j * 256 + tid;
      const int key = c >> 5, d0 = (c & 31) * 16;
      *(f16x8*)(Kld + key * 512 + (d0 ^ ((key & 7) << 4))) = kst[j];
    }
#pragma unroll
    for (int jj = 0; jj < 16; ++jj) {
      f16x2 pr;
      pr.x = (jj < 8) ? vst[0][jj & 7] : vst[1][jj & 7];  // key 2*kp
      pr.y = (jj < 8) ? vst[2][jj & 7] : vst[3][jj & 7];  // key 2*kp+1
      *(f16x2*)(Vld + (dch * 16 + jj) * 80 + kp * 4) = pr;
    }
  };

  stage_load(0);
  stage_write(0);
  __syncthreads();

  const int qa = qw + (lane & 15);

  for (int t = 0; t < NITP; ++t) {
    const int cur = t & 1;
    const int k0 = (g * NITP + t) * 32;

    // srel gather first (oldest in vmcnt FIFO)
    float srel[2][4];
#pragma unroll
    for (int nt = 0; nt < 2; ++nt)
#pragma unroll
      for (int j = 0; j < 4; ++j) {
        const int k = k0 + nt * 16 + gi * 4 + j;
        const int dq = k - qa;
        const size_t a1 = (size_t)qa * NL + (size_t)(NL - 1 + dq);
        const size_t a2 = (size_t)(qa + 1) * NL + (size_t)(dq - 2);
        const float v = (float)QEb[(dq <= 0) ? a1 : a2];
        srel[nt][j] = (dq == 1) ? 0.f : v;
      }

    if (t < NITP - 1) stage_load(t + 1);

    const char* Kld = smem + cur * KVBUF;
    const char* Vld = Kld + 16384;

    f32x4 s[2] = {f32x4{0.f, 0.f, 0.f, 0.f}, f32x4{0.f, 0.f, 0.f, 0.f}};
#pragma unroll
    for (int kk = 0; kk < 8; ++kk) {
      const int ko = kk * 64 + gi * 16;
#pragma unroll
      for (int nt = 0; nt < 2; ++nt) {
        const int key = nt * 16 + (lane & 15);
        f16x8 af = *(const f16x8*)(Kld + key * 512 + (ko ^ ((key & 7) << 4)));
        s[nt] = mfma16(af, qf[kk], s[nt]);
      }
    }

    float sv[2][4];
#pragma unroll
    for (int nt = 0; nt < 2; ++nt)
#pragma unroll
      for (int j = 0; j < 4; ++j) sv[nt][j] = 0.0625f * (s[nt][j] + srel[nt][j]);

    float pm = fmaxf(fmaxf(fmaxf(sv[0][0], sv[0][1]), fmaxf(sv[0][2], sv[0][3])),
                     fmaxf(fmaxf(sv[1][0], sv[1][1]), fmaxf(sv[1][2], sv[1][3])));
    pm = fmaxf(pm, __shfl_xor(pm, 16, 64));
    pm = fmaxf(pm, __shfl_xor(pm, 32, 64));

    float p[2][4];
    if (__any(pm > mrun + 8.f)) {
      const float mn = fmaxf(mrun, pm);
      const float al = __expf(mrun - mn);
      mrun = mn;
#pragma unroll
      for (int nt = 0; nt < 2; ++nt)
#pragma unroll
        for (int j = 0; j < 4; ++j) p[nt][j] = __expf(sv[nt][j] - mrun);
      float rs = (p[0][0] + p[0][1]) + (p[0][2] + p[0][3]) +
                 (p[1][0] + p[1][1]) + (p[1][2] + p[1][3]);
      rs += __shfl_xor(rs, 16, 64);
      rs += __shfl_xor(rs, 32, 64);
      lrun = lrun * al + rs;
#pragma unroll
      for (int j = 0; j < 4; ++j) {
        const float aj = __shfl(al, gi * 4 + j, 16);
#pragma unroll
        for (int dt = 0; dt < 16; ++dt) acc[dt][j] *= aj;
      }
    } else {
#pragma unroll
      for (int nt = 0; nt < 2; ++nt)
#pragma unroll
        for (int j = 0; j < 4; ++j) p[nt][j] = __expf(sv[nt][j] - mrun);
      float rs = (p[0][0] + p[0][1]) + (p[0][2] + p[0][3]) +
                 (p[1][0] + p[1][1]) + (p[1][2] + p[1][3]);
      rs += __shfl_xor(rs, 16, 64);
      rs += __shfl_xor(rs, 32, 64);
      lrun += rs;
    }

    union {
      fp16x2 h2[2];
      f16x4 h4;
    } pu0, pu1;
    pu0.h2[0] = __builtin_amdgcn_cvt_pkrtz(p[0][0], p[0][1]);
    pu0.h2[1] = __builtin_amdgcn_cvt_pkrtz(p[0][2], p[0][3]);
    pu1.h2[0] = __builtin_amdgcn_cvt_pkrtz(p[1][0], p[1][1]);
    pu1.h2[1] = __builtin_amdgcn_cvt_pkrtz(p[1][2], p[1][3]);

#pragma unroll
    for (int dt = 0; dt < 16; ++dt) {
      const char* vrow = Vld + (dt * 16 + (lane & 15)) * 80 + 8 * gi;
      f16x4 v0 = *(const f16x4*)(vrow);
      f16x4 v1 = *(const f16x4*)(vrow + 32);
      acc[dt] = __builtin_amdgcn_mfma_f32_16x16x16f16(pu0.h4, v0, acc[dt], 0, 0, 0);
      acc[dt] = __builtin_amdgcn_mfma_f32_16x16x16f16(pu1.h4, v1, acc[dt], 0, 0, 0);
    }

    if (t < NITP - 1) stage_write(cur ^ 1);  // other buffer: no reader this iter
    __syncthreads();                         // publish + fence before reuse
  }

  // ---- write l-normalized partials (f16) ----
  const float inv = 1.f / lrun;
  f16* Pb = Pac + ((size_t)g * (NB * NL) + (size_t)b * NL) * ND;
#pragma unroll
  for (int j = 0; j < 4; ++j) {
    const float invj = __shfl(inv, gi * 4 + j, 16);
    const int row = qw + gi * 4 + j;
#pragma unroll
    for (int dt = 0; dt < 16; ++dt)
      Pb[(size_t)row * ND + dt * 16 + (lane & 15)] = (f16)(acc[dt][j] * invj);
  }
  if (lane < 16) {
    const size_t r = (size_t)g * (NB * NL) + (size_t)b * NL + qw + lane;
    Pml[r * 2 + 0] = mrun;
    Pml[r * 2 + 1] = lrun;
  }
}

// ---------------- K4: combine 4 key-group normalized partials -> output
__global__ __launch_bounds__(256) void k4_comb(const f16* __restrict__ Pac,
                                               const float* __restrict__ Pml,
                                               float* __restrict__ Out) {
  const int row = blockIdx.x * 4 + (threadIdx.x >> 6);
  const int lane = threadIdx.x & 63;
  float m[4], l[4];
#pragma unroll
  for (int gq = 0; gq < 4; ++gq) {
    const size_t r = (size_t)gq * (NB * NL) + row;
    m[gq] = Pml[r * 2 + 0];
    l[gq] = Pml[r * 2 + 1];
  }
  const float M = fmaxf(fmaxf(m[0], m[1]), fmaxf(m[2], m[3]));
  float wgt[4];
  float denom = 0.f;
#pragma unroll
  for (int gq = 0; gq < 4; ++gq) {
    wgt[gq] = l[gq] * __expf(m[gq] - M);
    denom += wgt[gq];
  }
  const float inv = 1.f / denom;
  const size_t base = (size_t)row * ND + lane * 4;
  float o[4] = {0.f, 0.f, 0.f, 0.f};
#pragma unroll
  for (int gq = 0; gq < 4; ++gq) {
    f16x4 p = *(const f16x4*)(Pac + (size_t)gq * (NB * NL) * ND + base);
    const float s = wgt[gq] * inv;
#pragma unroll
    for (int e = 0; e < 4; ++e) o[e] += (float)p[e] * s;
  }
  f32x4 ov = {o[0], o[1], o[2], o[3]};
  *(f32x4*)(Out + base) = ov;
}

// ---------------- K3 fallback (r6): in-block 2-way key split, for small ws.
#define NIT 32
__global__ __launch_bounds__(512, 2) void k3_attn(
    const f16* __restrict__ Qh, const f16* __restrict__ Kh, const f16* __restrict__ Vh,
    const f16* __restrict__ QEh, float* __restrict__ Out) {
  extern __shared__ char smemd[];  // 73728 B
  const int b = blockIdx.y;
  const int q0 = blockIdx.x * 64;
  const int tid = threadIdx.x, lane = tid & 63, w = tid >> 6;
  const int g = w >> 2, wq = w & 3;
  const int qw = q0 + wq * 16;
  const int lt = tid & 255;
  const int gi = lane >> 4;

  float* Cst = (float*)smemd;
  float* ml = (float*)(smemd + 65536);

  const f16* Qb = Qh + (size_t)b * NL * ND;
  const f16* Kb = Kh + (size_t)b * NL * ND;
  const f16* Vb = Vh + (size_t)b * NL * ND;
  const f16* QEb = QEh + (size_t)b * NL * NL;

  f16x8 qf[8];
  {
    const int r = qw + (lane & 15);
#pragma unroll
    for (int kk = 0; kk < 8; ++kk)
      qf[kk] = *(const f16x8*)(Qb + (size_t)r * ND + kk * 32 + gi * 8);
  }

  f32x4 acc[16];
#pragma unroll
  for (int i = 0; i < 16; ++i) acc[i] = f32x4{0.f, 0.f, 0.f, 0.f};
  float mrun = -1e30f, lrun = 0.f;

  f16x8 kst[4], vst[4];
  const int kp = lt & 15, dch = lt >> 4;

  auto stage_load = [&](int t) {
    const f16* Ks = Kb + (size_t)(g * NIT + t) * 32 * ND;
#pragma unroll
    for (int j = 0; j < 4; ++j) {
      const int c = j * 256 + lt;
      kst[j] = *(const f16x8*)(Ks + (c >> 5) * ND + (c & 31) * 8);
    }
    const f16* Vs = Vb + (size_t)(g * NIT + t) * 32 * ND;
    vst[0] = *(const f16x8*)(Vs + (2 * kp) * ND + dch * 16);
    vst[1] = *(const f16x8*)(Vs + (2 * kp) * ND + dch * 16 + 8);
    vst[2] = *(const f16x8*)(Vs + (2 * kp + 1) * ND + dch * 16);
    vst[3] = *(const f16x8*)(Vs + (2 * kp + 1) * ND + dch * 16 + 8);
  };
  auto stage_write = [&]() {
    char* Kld = smemd + g * KVBUF;
    char* Vld = Kld + 16384;
#pragma unroll
    for (int j = 0; j < 4; ++j) {
      const int c = j * 256 + lt;
      const int key = c >> 5, d0 = (c & 31) * 16;
      *(f16x8*)(Kld + key * 512 + (d0 ^ ((key & 7) << 4))) = kst[j];
    }
#pragma unroll
    for (int jj = 0; jj < 16; ++jj) {
      f16x2 pr;
      pr.x = (jj < 8) ? vst[0][jj & 7] : vst[1][jj & 7];
      pr.y = (jj < 8) ? vst[2][jj & 7] : vst[3][jj & 7];
      *(f16x2*)(Vld + (dch * 16 + jj) * 80 + kp * 4) = pr;
    }
  };

  stage_load(0);
  stage_write();
  __syncthreads();

  const int qa = qw + (lane & 15);

  for (int t = 0; t < NIT; ++t) {
    const int k0 = (g * NIT + t) * 32;

    float srel[2][4];
#pragma unroll
    for (int nt = 0; nt < 2; ++nt)
#pragma unroll
      for (int j = 0; j < 4; ++j) {
        const int k = k0 + nt * 16 + gi * 4 + j;
        const int dq = k - qa;
        const size_t a1 = (size_t)qa * NL + (size_t)(NL - 1 + dq);
        const size_t a2 = (size_t)(qa + 1) * NL + (size_t)(dq - 2);
        const float v = (float)QEb[(dq <= 0) ? a1 : a2];
        srel[nt][j] = (dq == 1) ? 0.f : v;
      }

    if (t < NIT - 1) stage_load(t + 1);

    const char* Kld = smemd + g * KVBUF;
    const char* Vld = Kld + 16384;

    f32x4 s[2] = {f32x4{0.f, 0.f, 0.f, 0.f}, f32x4{0.f, 0.f, 0.f, 0.f}};
#pragma unroll
    for (int kk = 0; kk < 8; ++kk) {
      const int ko = kk * 64 + gi * 16;
#pragma unroll
      for (int nt = 0; nt < 2; ++nt) {
        const int key = nt * 16 + (lane & 15);
        f16x8 af = *(const f16x8*)(Kld + key * 512 + (ko ^ ((key & 7) << 4)));
        s[nt] = mfma16(af, qf[kk], s[nt]);
      }
    }

    float sv[2][4];
#pragma unroll
    for (int nt = 0; nt < 2; ++nt)
#pragma unroll
      for (int j = 0; j < 4; ++j) sv[nt][j] = 0.0625f * (s[nt][j] + srel[nt][j]);

    float pm = fmaxf(fmaxf(fmaxf(sv[0][0], sv[0][1]), fmaxf(sv[0][2], sv[0][3])),
                     fmaxf(fmaxf(sv[1][0], sv[1][1]), fmaxf(sv[1][2], sv[1][3])));
    pm = fmaxf(pm, __shfl_xor(pm, 16, 64));
    pm = fmaxf(pm, __shfl_xor(pm, 32, 64));

    float p[2][4];
    if (__any(pm > mrun + 8.f)) {
      const float mn = fmaxf(mrun, pm);
      const float al = __expf(mrun - mn);
      mrun = mn;
#pragma unroll
      for (int nt = 0; nt < 2; ++nt)
#pragma unroll
        for (int j = 0; j < 4; ++j) p[nt][j] = __expf(sv[nt][j] - mrun);
      float rs = (p[0][0] + p[0][1]) + (p[0][2] + p[0][3]) +
                 (p[1][0] + p[1][1]) + (p[1][2] + p[1][3]);
      rs += __shfl_xor(rs, 16, 64);
      rs += __shfl_xor(rs, 32, 64);
      lrun = lrun * al + rs;
#pragma unroll
      for (int j = 0; j < 4; ++j) {
        const float aj = __shfl(al, gi * 4 + j, 16);
#pragma unroll
        for (int dt = 0; dt < 16; ++dt) acc[dt][j] *= aj;
      }
    } else {
#pragma unroll
      for (int nt = 0; nt < 2; ++nt)
#pragma unroll
        for (int j = 0; j < 4; ++j) p[nt][j] = __expf(sv[nt][j] - mrun);
      float rs = (p[0][0] + p[0][1]) + (p[0][2] + p[0][3]) +
                 (p[1][0] + p[1][1]) + (p[1][2] + p[1][3]);
      rs += __shfl_xor(rs, 16, 64);
      rs += __shfl_xor(rs, 32, 64);
      lrun += rs;
    }

    union {
      fp16x2 h2[2];
      f16x4 h4;
    } pu0, pu1;
    pu0.h2[0] = __builtin_amdgcn_cvt_pkrtz(p[0][0], p[0][1]);
    pu0.h2[1] = __builtin_amdgcn_cvt_pkrtz(p[0][2], p[0][3]);
    pu1.h2[0] = __builtin_amdgcn_cvt_pkrtz(p[1][0], p[1][1]);
    pu1.h2[1] = __builtin_amdgcn_cvt_pkrtz(p[1][2], p[1][3]);

#pragma unroll
    for (int dt = 0; dt < 16; ++dt) {
      const char* vrow = Vld + (dt * 16 + (lane & 15)) * 80 + 8 * gi;
      f16x4 v0 = *(const f16x4*)(vrow);
      f16x4 v1 = *(const f16x4*)(vrow + 32);
      acc[dt] = __builtin_amdgcn_mfma_f32_16x16x16f16(pu0.h4, v0, acc[dt], 0, 0, 0);
      acc[dt] = __builtin_amdgcn_mfma_f32_16x16x16f16(pu1.h4, v1, acc[dt], 0, 0, 0);
    }

    __syncthreads();
    if (t < NIT - 1) stage_write();
    __syncthreads();
  }

  if (g == 1) {
#pragma unroll
    for (int dt = 0; dt < 16; ++dt)
#pragma unroll
      for (int j = 0; j < 4; ++j)
        Cst[wq * 4096 + (gi * 4 + j) * 256 + dt * 16 + (lane & 15)] = acc[dt][j];
    if (lane < 16) {
      ml[(wq * 16 + lane) * 2 + 0] = mrun;
      ml[(wq * 16 + lane) * 2 + 1] = lrun;
    }
  }
  __syncthreads();
  if (g == 0) {
    float* Ob = Out + (size_t)b * NL * ND;
#pragma unroll
    for (int j = 0; j < 4; ++j) {
      const int rloc = gi * 4 + j;
      const float m0r = __shfl(mrun, rloc, 16);
      const float l0r = __shfl(lrun, rloc, 16);
      const float m1 = ml[(wq * 16 + rloc) * 2 + 0];
      const float l1 = ml[(wq * 16 + rloc) * 2 + 1];
      const float M = fmaxf(m0r, m1);
      const float c0 = __expf(m0r - M), c1 = __expf(m1 - M);
      const float inv = 1.f / (l0r * c0 + l1 * c1);
      const int row = qw + rloc;
#pragma unroll
      for (int dt = 0; dt < 16; ++dt) {
        const float o1 = Cst[wq * 4096 + rloc * 256 + dt * 16 + (lane & 15)];
        Ob[(size_t)row * ND + dt * 16 + (lane & 15)] = (acc[dt][j] * c0 + o1 * c1) * inv;
      }
    }
  }
}

extern "C" void kernel_launch(void* const* d_in, const int* in_sizes, int n_in,
                              void* d_out, int out_size, void* d_ws, size_t ws_size,
                              hipStream_t stream) {
  (void)in_sizes; (void)n_in; (void)out_size;
  const float* inQ = (const float*)d_in[0];
  const float* inK = (const float*)d_in[1];
  const float* inV = (const float*)d_in[2];
  const float* Wq = (const float*)d_in[3];
  const float* Wk = (const float*)d_in[4];
  const float* Wv = (const float*)d_in[5];
  float* out = (float*)d_out;

  // ws layout (f16): Qh,Kh,Vh [B*L*D]; WT [3*256*256]; QEh [B*L*L];
  // Pac f16 [4][B*L][D]; then (f32) Pml [4][B*L][2].
  f16* ws = (f16*)d_ws;
  f16* Qh = ws;
  f16* Kh = Qh + (size_t)QKV_ELEMS;
  f16* Vh = Kh + (size_t)QKV_ELEMS;
  f16* WT = Vh + (size_t)QKV_ELEMS;
  f16* QEh = WT + 3 * 65536;
  f16* Pac = QEh + (size_t)NB * NL * NL;
  float* Pml = (float*)(Pac + (size_t)4 * QKV_ELEMS);
  const size_t need = (size_t)((char*)(Pml + 4 * NB * NL * 2) - (char*)d_ws);

  k0_wt<<<dim3(768), dim3(256), 0, stream>>>(Wq, Wk, Wv, WT);
  k1_proj<<<dim3(256, 3), dim3(256), 0, stream>>>(inQ, inK, inV, WT, Qh, Kh, Vh);
  k2_qe<<<dim3(16, 16, 8), dim3(256), 0, stream>>>(Qh, Kh, QEh);
  if (ws_size >= need) {
    k3_part<<<dim3(32, 8, 4), dim3(256), 2 * KVBUF, stream>>>(Qh, Kh, Vh, QEh, Pac, Pml);
    k4_comb<<<dim3(NB * NL / 4), dim3(256), 0, stream>>>(Pac, Pml, out);
  } else {
    k3_attn<<<dim3(32, 8), dim3(512), 73728, stream>>>(Qh, Kh, Vh, QEh, out);
  }
}

// Round 17
// 184.948 us; speedup vs baseline: 1.1267x; 1.0232x over previous
//
#include <hip/hip_runtime.h>
#include <hip/hip_fp16.h>
#include <stdint.h>

typedef _Float16 f16;
typedef _Float16 f16x2 __attribute__((ext_vector_type(2)));
typedef _Float16 f16x4 __attribute__((ext_vector_type(4)));
typedef _Float16 f16x8 __attribute__((ext_vector_type(8)));
typedef __fp16 fp16x2 __attribute__((ext_vector_type(2)));  // cvt_pkrtz return type
typedef float f32x4 __attribute__((ext_vector_type(4)));

#define NB 8
#define NL 2048
#define ND 256
#define QKV_ELEMS (NB * NL * ND)   // 4194304

__device__ __forceinline__ f32x4 mfma16(f16x8 a, f16x8 b, f32x4 c) {
  return __builtin_amdgcn_mfma_f32_16x16x32_f16(a, b, c, 0, 0, 0);
}

// ---------------- K0: transpose+convert weights: WT[m][n][k] = (f16)W_m[k][n]
__global__ void k0_wt(const float* __restrict__ Wq, const float* __restrict__ Wk,
                      const float* __restrict__ Wv, f16* __restrict__ WT) {
  int id = blockIdx.x * 256 + threadIdx.x;  // 0..196607
  int m = id >> 16;
  int r = id & 65535;
  int k = r >> 8, n = r & 255;
  const float* W = (m == 0) ? Wq : (m == 1) ? Wk : Wv;
  WT[m * 65536 + n * 256 + k] = (f16)W[k * 256 + n];
}

// ---------------- K1: projections (fp32 A, f16 MFMA, f16 out). 64 rows/block.
__global__ __launch_bounds__(256) void k1_proj(
    const float* __restrict__ Aq, const float* __restrict__ Ak, const float* __restrict__ Av,
    const f16* __restrict__ WT, f16* __restrict__ Qh, f16* __restrict__ Kh,
    f16* __restrict__ Vh) {
  const int m = blockIdx.y;
  const float* A = (m == 0) ? Aq : (m == 1) ? Ak : Av;
  f16* O = (m == 0) ? Qh : (m == 1) ? Kh : Vh;
  const f16* Wm = WT + m * 65536;
  const int row0 = blockIdx.x * 64;
  const int tid = threadIdx.x;
  const int lane = tid & 63, w = tid >> 6;

  __shared__ f16 Ald[64 * 64];    // [r][k], swizzled ((r&7)<<4) on byte offset
  __shared__ f16 Wld[256 * 64];   // [n][k], swizzled ((n&7)<<4)

  f32x4 acc[16];
#pragma unroll
  for (int i = 0; i < 16; ++i) acc[i] = f32x4{0.f, 0.f, 0.f, 0.f};

  for (int kb = 0; kb < 4; ++kb) {
    __syncthreads();
    {  // stage A tile 64x64 fp32 -> f16
      const int r = tid >> 2, c0 = (tid & 3) * 16;
      const float* src = A + (size_t)(row0 + r) * ND + kb * 64 + c0;
      f16x8 h0, h1;
#pragma unroll
      for (int j = 0; j < 8; ++j) h0[j] = (f16)src[j];
#pragma unroll
      for (int j = 0; j < 8; ++j) h1[j] = (f16)src[8 + j];
      const int sw = (r & 7) << 4;
      *(f16x8*)((char*)Ald + r * 128 + ((c0 * 2) ^ sw)) = h0;
      *(f16x8*)((char*)Ald + r * 128 + ((c0 * 2 + 16) ^ sw)) = h1;
    }
    {  // stage WT tile [256][64] f16
      const int n = tid;
      const f16* src = Wm + n * 256 + kb * 64;
      const int sw = (n & 7) << 4;
#pragma unroll
      for (int j = 0; j < 8; ++j) {
        f16x8 v = *(const f16x8*)(src + j * 8);
        *(f16x8*)((char*)Wld + n * 128 + ((j * 16) ^ sw)) = v;
      }
    }
    __syncthreads();
#pragma unroll
    for (int kk = 0; kk < 2; ++kk) {
      const int arow = w * 16 + (lane & 15);
      const int ko = kk * 64 + (lane >> 4) * 16;
      f16x8 a = *(const f16x8*)((char*)Ald + arow * 128 + (ko ^ ((arow & 7) << 4)));
#pragma unroll
      for (int nt = 0; nt < 16; ++nt) {
        const int n = nt * 16 + (lane & 15);
        f16x8 b = *(const f16x8*)((char*)Wld + n * 128 + (ko ^ ((n & 7) << 4)));
        acc[nt] = mfma16(a, b, acc[nt]);
      }
    }
  }
  const int rl = (lane >> 4) * 4;
#pragma unroll
  for (int nt = 0; nt < 16; ++nt) {
    const int col = nt * 16 + (lane & 15);
#pragma unroll
    for (int j = 0; j < 4; ++j)
      O[(size_t)(row0 + w * 16 + rl + j) * ND + col] = (f16)acc[nt][j];
  }
}

// ---------------- K2: Srel[b] = skew(Q[b] @ (K[b]-Q[b])^T), 128x128 tile.
// E = K - Q computed during B-tile staging. Epilogue writes each QE element
// DIRECTLY to its skew target (bijection):
//   QE[r][c] -> Srel[r][c+r-(L-1)]    if c >= L-1-r
//           -> Srel[r-1][c+r+1]       else (dropped when r==0)
// Only Srel[q][q+1] cells stay unwritten (the zero column; masked in k3).
// This makes k3's srel gather ROW-CONTIGUOUS (vectorizable) instead of
// 8 scattered scalar loads ~4KB apart across lanes.
__global__ __launch_bounds__(256) void k2_qe(const f16* __restrict__ Qh,
                                             const f16* __restrict__ Kh,
                                             f16* __restrict__ QEh) {
  const int b = blockIdx.z;
  const int m0 = blockIdx.x * 128, n0 = blockIdx.y * 128;
  const int tid = threadIdx.x, lane = tid & 63, w = tid >> 6;
  const int wr = (w >> 1) * 64, wc = (w & 1) * 64;
  const f16* Qb = Qh + (size_t)b * NL * ND;
  const f16* Kb = Kh + (size_t)b * NL * ND;

  __shared__ f16 As[128 * 64];  // [r][k] swizzled ((r&7)<<4)
  __shared__ f16 Bs[128 * 64];

  f32x4 acc[4][4];
#pragma unroll
  for (int i = 0; i < 4; ++i)
#pragma unroll
    for (int j = 0; j < 4; ++j) acc[i][j] = f32x4{0.f, 0.f, 0.f, 0.f};

  for (int kb = 0; kb < 4; ++kb) {
    __syncthreads();
#pragma unroll
    for (int j = 0; j < 4; ++j) {
      const int c = j * 256 + tid;       // 1024 chunks of 16B
      const int r = c >> 3;
      const int ko = (c & 7) * 16;       // byte offset in row
      const int sw = (r & 7) << 4;
      f16x8 va = *(const f16x8*)((const char*)(Qb + (size_t)(m0 + r) * ND + kb * 64) + ko);
      *(f16x8*)((char*)As + r * 128 + (ko ^ sw)) = va;
      f16x8 vk = *(const f16x8*)((const char*)(Kb + (size_t)(n0 + r) * ND + kb * 64) + ko);
      f16x8 vq = *(const f16x8*)((const char*)(Qb + (size_t)(n0 + r) * ND + kb * 64) + ko);
      *(f16x8*)((char*)Bs + r * 128 + (ko ^ sw)) = vk - vq;  // E = K - Q
    }
    __syncthreads();
#pragma unroll
    for (int kk = 0; kk < 2; ++kk) {
      const int ko = kk * 64 + (lane >> 4) * 16;
      f16x8 a[4], bf[4];
#pragma unroll
      for (int mt = 0; mt < 4; ++mt) {
        const int r = wr + mt * 16 + (lane & 15);
        a[mt] = *(const f16x8*)((char*)As + r * 128 + (ko ^ ((r & 7) << 4)));
      }
#pragma unroll
      for (int nt = 0; nt < 4; ++nt) {
        const int r = wc + nt * 16 + (lane & 15);
        bf[nt] = *(const f16x8*)((char*)Bs + r * 128 + (ko ^ ((r & 7) << 4)));
      }
#pragma unroll
      for (int mt = 0; mt < 4; ++mt)
#pragma unroll
        for (int nt = 0; nt < 4; ++nt) acc[mt][nt] = mfma16(a[mt], bf[nt], acc[mt][nt]);
    }
  }
  f16* outb = QEh + (size_t)b * NL * NL;
#pragma unroll
  for (int mt = 0; mt < 4; ++mt)
#pragma unroll
    for (int nt = 0; nt < 4; ++nt) {
      const int col = n0 + wc + nt * 16 + (lane & 15);
#pragma unroll
      for (int j = 0; j < 4; ++j) {
        const int row = m0 + wr + mt * 16 + (lane >> 4) * 4 + j;
        int qrow, kk2;
        if (col >= (NL - 1) - row) { qrow = row; kk2 = col + row - (NL - 1); }
        else { qrow = row - 1; kk2 = col + row + 1; }
        if (qrow >= 0)
          outb[(size_t)qrow * NL + kk2] = (f16)acc[mt][nt][j];
      }
    }
}

// ---------------- K3p: 4-way key-split flash attention partials.
// r16 form (dbuf K/V, one barrier/iter) + SKEWED-Srel row-contiguous gather:
// per lane 2x f16x4 vector loads (8 consecutive f16) instead of 8 scattered
// scalars; Srel[q][q+1] (unwritten zero column) masked in-register.
#define KVBUF 36864   // 16384 (K [32][256] swz) + 20480 (V [256][40])
#define NITP 16
__global__ __launch_bounds__(256, 2) void k3_part(
    const f16* __restrict__ Qh, const f16* __restrict__ Kh, const f16* __restrict__ Vh,
    const f16* __restrict__ QEh, f16* __restrict__ Pac, float* __restrict__ Pml) {
  extern __shared__ char smem[];  // 2 * KVBUF = 73728 B
  const int b = blockIdx.y;
  const int g = blockIdx.z;
  const int q0 = blockIdx.x * 64;
  const int tid = threadIdx.x, lane = tid & 63, w = tid >> 6;
  const int qw = q0 + w * 16;
  const int gi = lane >> 4;

  const f16* Qb = Qh + (size_t)b * NL * ND;
  const f16* Kb = Kh + (size_t)b * NL * ND;
  const f16* Vb = Vh + (size_t)b * NL * ND;
  const f16* QEb = QEh + (size_t)b * NL * NL;  // skewed Srel layout

  f16x8 qf[8];
  {
    const int r = qw + (lane & 15);
#pragma unroll
    for (int kk = 0; kk < 8; ++kk)
      qf[kk] = *(const f16x8*)(Qb + (size_t)r * ND + kk * 32 + gi * 8);
  }

  f32x4 acc[16];
#pragma unroll
  for (int i = 0; i < 16; ++i) acc[i] = f32x4{0.f, 0.f, 0.f, 0.f};
  float mrun = -1e30f, lrun = 0.f;

  f16x8 kst[4], vst[4];
  const int kp = tid & 15, dch = tid >> 4;

  auto stage_load = [&](int t) {
    const f16* Ks = Kb + (size_t)(g * NITP + t) * 32 * ND;
#pragma unroll
    for (int j = 0; j < 4; ++j) {
      const int c = j * 256 + tid;
      kst[j] = *(const f16x8*)(Ks + (c >> 5) * ND + (c & 31) * 8);
    }
    const f16* Vs = Vb + (size_t)(g * NITP + t) * 32 * ND;
    vst[0] = *(const f16x8*)(Vs + (2 * kp) * ND + dch * 16);
    vst[1] = *(const f16x8*)(Vs + (2 * kp) * ND + dch * 16 + 8);
    vst[2] = *(const f16x8*)(Vs + (2 * kp + 1) * ND + dch * 16);
    vst[3] = *(const f16x8*)(Vs + (2 * kp + 1) * ND + dch * 16 + 8);
  };
  auto stage_write = [&](int buf) {
    char* Kld = smem + buf * KVBUF;
    char* Vld = Kld + 16384;
#pragma unroll
    for (int j = 0; j < 4; ++j) {
      const int c = j * 256 + tid;
      const int key = c >> 5, d0 = (c & 31) * 16;
      *(f16x8*)(Kld + key * 512 + (d0 ^ ((key & 7) << 4))) = kst[j];
    }
#pragma unroll
    for (int jj = 0; jj < 16; ++jj) {
      f16x2 pr;
      pr.x = (jj < 8) ? vst[0][jj & 7] : vst[1][jj & 7];  // key 2*kp
      pr.y = (jj < 8) ? vst[2][jj & 7] : vst[3][jj & 7];  // key 2*kp+1
      *(f16x2*)(Vld + (dch * 16 + jj) * 80 + kp * 4) = pr;
    }
  };

  stage_load(0);
  stage_write(0);
  __syncthreads();

  const int qa = qw + (lane & 15);

  for (int t = 0; t < NITP; ++t) {
    const int cur = t & 1;
    const int k0 = (g * NITP + t) * 32;

    // srel gather: ROW-CONTIGUOUS from skewed Srel (2 vector loads/lane)
    float srel[2][4];
#pragma unroll
    for (int nt = 0; nt < 2; ++nt) {
      const int kb2 = k0 + nt * 16 + gi * 4;
      f16x4 v4 = *(const f16x4*)(QEb + (size_t)qa * NL + kb2);
#pragma unroll
      for (int j = 0; j < 4; ++j)
        srel[nt][j] = (kb2 + j == qa + 1) ? 0.f : (float)v4[j];
    }

    if (t < NITP - 1) stage_load(t + 1);

    const char* Kld = smem + cur * KVBUF;
    const char* Vld = Kld + 16384;

    f32x4 s[2] = {f32x4{0.f, 0.f, 0.f, 0.f}, f32x4{0.f, 0.f, 0.f, 0.f}};
#pragma unroll
    for (int kk = 0; kk < 8; ++kk) {
      const int ko = kk * 64 + gi * 16;
#pragma unroll
      for (int nt = 0; nt < 2; ++nt) {
        const int key = nt * 16 + (lane & 15);
        f16x8 af = *(const f16x8*)(Kld + key * 512 + (ko ^ ((key & 7) << 4)));
        s[nt] = mfma16(af, qf[kk], s[nt]);
      }
    }

    float sv[2][4];
#pragma unroll
    for (int nt = 0; nt < 2; ++nt)
#pragma unroll
      for (int j = 0; j < 4; ++j) sv[nt][j] = 0.0625f * (s[nt][j] + srel[nt][j]);

    float pm = fmaxf(fmaxf(fmaxf(sv[0][0], sv[0][1]), fmaxf(sv[0][2], sv[0][3])),
                     fmaxf(fmaxf(sv[1][0], sv[1][1]), fmaxf(sv[1][2], sv[1][3])));
    pm = fmaxf(pm, __shfl_xor(pm, 16, 64));
    pm = fmaxf(pm, __shfl_xor(pm, 32, 64));

    float p[2][4];
    if (__any(pm > mrun + 8.f)) {
      const float mn = fmaxf(mrun, pm);
      const float al = __expf(mrun - mn);
      mrun = mn;
#pragma unroll
      for (int nt = 0; nt < 2; ++nt)
#pragma unroll
        for (int j = 0; j < 4; ++j) p[nt][j] = __expf(sv[nt][j] - mrun);
      float rs = (p[0][0] + p[0][1]) + (p[0][2] + p[0][3]) +
                 (p[1][0] + p[1][1]) + (p[1][2] + p[1][3]);
      rs += __shfl_xor(rs, 16, 64);
      rs += __shfl_xor(rs, 32, 64);
      lrun = lrun * al + rs;
#pragma unroll
      for (int j = 0; j < 4; ++j) {
        const float aj = __shfl(al, gi * 4 + j, 16);
#pragma unroll
        for (int dt = 0; dt < 16; ++dt) acc[dt][j] *= aj;
      }
    } else {
#pragma unroll
      for (int nt = 0; nt < 2; ++nt)
#pragma unroll
        for (int j = 0; j < 4; ++j) p[nt][j] = __expf(sv[nt][j] - mrun);
      float rs = (p[0][0] + p[0][1]) + (p[0][2] + p[0][3]) +
                 (p[1][0] + p[1][1]) + (p[1][2] + p[1][3]);
      rs += __shfl_xor(rs, 16, 64);
      rs += __shfl_xor(rs, 32, 64);
      lrun += rs;
    }

    union {
      fp16x2 h2[2];
      f16x4 h4;
    } pu0, pu1;
    pu0.h2[0] = __builtin_amdgcn_cvt_pkrtz(p[0][0], p[0][1]);
    pu0.h2[1] = __builtin_amdgcn_cvt_pkrtz(p[0][2], p[0][3]);
    pu1.h2[0] = __builtin_amdgcn_cvt_pkrtz(p[1][0], p[1][1]);
    pu1.h2[1] = __builtin_amdgcn_cvt_pkrtz(p[1][2], p[1][3]);

#pragma unroll
    for (int dt = 0; dt < 16; ++dt) {
      const char* vrow = Vld + (dt * 16 + (lane & 15)) * 80 + 8 * gi;
      f16x4 v0 = *(const f16x4*)(vrow);
      f16x4 v1 = *(const f16x4*)(vrow + 32);
      acc[dt] = __builtin_amdgcn_mfma_f32_16x16x16f16(pu0.h4, v0, acc[dt], 0, 0, 0);
      acc[dt] = __builtin_amdgcn_mfma_f32_16x16x16f16(pu1.h4, v1, acc[dt], 0, 0, 0);
    }

    if (t < NITP - 1) stage_write(cur ^ 1);  // other buffer: no reader this iter
    __syncthreads();                         // publish + fence before reuse
  }

  // ---- write l-normalized partials (f16) ----
  const float inv = 1.f / lrun;
  f16* Pb = Pac + ((size_t)g * (NB * NL) + (size_t)b * NL) * ND;
#pragma unroll
  for (int j = 0; j < 4; ++j) {
    const float invj = __shfl(inv, gi * 4 + j, 16);
    const int row = qw + gi * 4 + j;
#pragma unroll
    for (int dt = 0; dt < 16; ++dt)
      Pb[(size_t)row * ND + dt * 16 + (lane & 15)] = (f16)(acc[dt][j] * invj);
  }
  if (lane < 16) {
    const size_t r = (size_t)g * (NB * NL) + (size_t)b * NL + qw + lane;
    Pml[r * 2 + 0] = mrun;
    Pml[r * 2 + 1] = lrun;
  }
}

// ---------------- K4: combine 4 key-group normalized partials -> output
__global__ __launch_bounds__(256) void k4_comb(const f16* __restrict__ Pac,
                                               const float* __restrict__ Pml,
                                               float* __restrict__ Out) {
  const int row = blockIdx.x * 4 + (threadIdx.x >> 6);
  const int lane = threadIdx.x & 63;
  float m[4], l[4];
#pragma unroll
  for (int gq = 0; gq < 4; ++gq) {
    const size_t r = (size_t)gq * (NB * NL) + row;
    m[gq] = Pml[r * 2 + 0];
    l[gq] = Pml[r * 2 + 1];
  }
  const float M = fmaxf(fmaxf(m[0], m[1]), fmaxf(m[2], m[3]));
  float wgt[4];
  float denom = 0.f;
#pragma unroll
  for (int gq = 0; gq < 4; ++gq) {
    wgt[gq] = l[gq] * __expf(m[gq] - M);
    denom += wgt[gq];
  }
  const float inv = 1.f / denom;
  const size_t base = (size_t)row * ND + lane * 4;
  float o[4] = {0.f, 0.f, 0.f, 0.f};
#pragma unroll
  for (int gq = 0; gq < 4; ++gq) {
    f16x4 p = *(const f16x4*)(Pac + (size_t)gq * (NB * NL) * ND + base);
    const float s = wgt[gq] * inv;
#pragma unroll
    for (int e = 0; e < 4; ++e) o[e] += (float)p[e] * s;
  }
  f32x4 ov = {o[0], o[1], o[2], o[3]};
  *(f32x4*)(Out + base) = ov;
}

// ---------------- K3 fallback (r6 form, skewed-Srel gather), for small ws.
#define NIT 32
__global__ __launch_bounds__(512, 2) void k3_attn(
    const f16* __restrict__ Qh, const f16* __restrict__ Kh, const f16* __restrict__ Vh,
    const f16* __restrict__ QEh, float* __restrict__ Out) {
  extern __shared__ char smemd[];  // 73728 B
  const int b = blockIdx.y;
  const int q0 = blockIdx.x * 64;
  const int tid = threadIdx.x, lane = tid & 63, w = tid >> 6;
  const int g = w >> 2, wq = w & 3;
  const int qw = q0 + wq * 16;
  const int lt = tid & 255;
  const int gi = lane >> 4;

  float* Cst = (float*)smemd;
  float* ml = (float*)(smemd + 65536);

  const f16* Qb = Qh + (size_t)b * NL * ND;
  const f16* Kb = Kh + (size_t)b * NL * ND;
  const f16* Vb = Vh + (size_t)b * NL * ND;
  const f16* QEb = QEh + (size_t)b * NL * NL;  // skewed Srel layout

  f16x8 qf[8];
  {
    const int r = qw + (lane & 15);
#pragma unroll
    for (int kk = 0; kk < 8; ++kk)
      qf[kk] = *(const f16x8*)(Qb + (size_t)r * ND + kk * 32 + gi * 8);
  }

  f32x4 acc[16];
#pragma unroll
  for (int i = 0; i < 16; ++i) acc[i] = f32x4{0.f, 0.f, 0.f, 0.f};
  float mrun = -1e30f, lrun = 0.f;

  f16x8 kst[4], vst[4];
  const int kp = lt & 15, dch = lt >> 4;

  auto stage_load = [&](int t) {
    const f16* Ks = Kb + (size_t)(g * NIT + t) * 32 * ND;
#pragma unroll
    for (int j = 0; j < 4; ++j) {
      const int c = j * 256 + lt;
      kst[j] = *(const f16x8*)(Ks + (c >> 5) * ND + (c & 31) * 8);
    }
    const f16* Vs = Vb + (size_t)(g * NIT + t) * 32 * ND;
    vst[0] = *(const f16x8*)(Vs + (2 * kp) * ND + dch * 16);
    vst[1] = *(const f16x8*)(Vs + (2 * kp) * ND + dch * 16 + 8);
    vst[2] = *(const f16x8*)(Vs + (2 * kp + 1) * ND + dch * 16);
    vst[3] = *(const f16x8*)(Vs + (2 * kp + 1) * ND + dch * 16 + 8);
  };
  auto stage_write = [&]() {
    char* Kld = smemd + g * KVBUF;
    char* Vld = Kld + 16384;
#pragma unroll
    for (int j = 0; j < 4; ++j) {
      const int c = j * 256 + lt;
      const int key = c >> 5, d0 = (c & 31) * 16;
      *(f16x8*)(Kld + key * 512 + (d0 ^ ((key & 7) << 4))) = kst[j];
    }
#pragma unroll
    for (int jj = 0; jj < 16; ++jj) {
      f16x2 pr;
      pr.x = (jj < 8) ? vst[0][jj & 7] : vst[1][jj & 7];
      pr.y = (jj < 8) ? vst[2][jj & 7] : vst[3][jj & 7];
      *(f16x2*)(Vld + (dch * 16 + jj) * 80 + kp * 4) = pr;
    }
  };

  stage_load(0);
  stage_write();
  __syncthreads();

  const int qa = qw + (lane & 15);

  for (int t = 0; t < NIT; ++t) {
    const int k0 = (g * NIT + t) * 32;

    float srel[2][4];
#pragma unroll
    for (int nt = 0; nt < 2; ++nt) {
      const int kb2 = k0 + nt * 16 + gi * 4;
      f16x4 v4 = *(const f16x4*)(QEb + (size_t)qa * NL + kb2);
#pragma unroll
      for (int j = 0; j < 4; ++j)
        srel[nt][j] = (kb2 + j == qa + 1) ? 0.f : (float)v4[j];
    }

    if (t < NIT - 1) stage_load(t + 1);

    const char* Kld = smemd + g * KVBUF;
    const char* Vld = Kld + 16384;

    f32x4 s[2] = {f32x4{0.f, 0.f, 0.f, 0.f}, f32x4{0.f, 0.f, 0.f, 0.f}};
#pragma unroll
    for (int kk = 0; kk < 8; ++kk) {
      const int ko = kk * 64 + gi * 16;
#pragma unroll
      for (int nt = 0; nt < 2; ++nt) {
        const int key = nt * 16 + (lane & 15);
        f16x8 af = *(const f16x8*)(Kld + key * 512 + (ko ^ ((key & 7) << 4)));
        s[nt] = mfma16(af, qf[kk], s[nt]);
      }
    }

    float sv[2][4];
#pragma unroll
    for (int nt = 0; nt < 2; ++nt)
#pragma unroll
      for (int j = 0; j < 4; ++j) sv[nt][j] = 0.0625f * (s[nt][j] + srel[nt][j]);

    float pm = fmaxf(fmaxf(fmaxf(sv[0][0], sv[0][1]), fmaxf(sv[0][2], sv[0][3])),
                     fmaxf(fmaxf(sv[1][0], sv[1][1]), fmaxf(sv[1][2], sv[1][3])));
    pm = fmaxf(pm, __shfl_xor(pm, 16, 64));
    pm = fmaxf(pm, __shfl_xor(pm, 32, 64));

    float p[2][4];
    if (__any(pm > mrun + 8.f)) {
      const float mn = fmaxf(mrun, pm);
      const float al = __expf(mrun - mn);
      mrun = mn;
#pragma unroll
      for (int nt = 0; nt < 2; ++nt)
#pragma unroll
        for (int j = 0; j < 4; ++j) p[nt][j] = __expf(sv[nt][j] - mrun);
      float rs = (p[0][0] + p[0][1]) + (p[0][2] + p[0][3]) +
                 (p[1][0] + p[1][1]) + (p[1][2] + p[1][3]);
      rs += __shfl_xor(rs, 16, 64);
      rs += __shfl_xor(rs, 32, 64);
      lrun = lrun * al + rs;
#pragma unroll
      for (int j = 0; j < 4; ++j) {
        const float aj = __shfl(al, gi * 4 + j, 16);
#pragma unroll
        for (int dt = 0; dt < 16; ++dt) acc[dt][j] *= aj;
      }
    } else {
#pragma unroll
      for (int nt = 0; nt < 2; ++nt)
#pragma unroll
        for (int j = 0; j < 4; ++j) p[nt][j] = __expf(sv[nt][j] - mrun);
      float rs = (p[0][0] + p[0][1]) + (p[0][2] + p[0][3]) +
                 (p[1][0] + p[1][1]) + (p[1][2] + p[1][3]);
      rs += __shfl_xor(rs, 16, 64);
      rs += __shfl_xor(rs, 32, 64);
      lrun += rs;
    }

    union {
      fp16x2 h2[2];
      f16x4 h4;
    } pu0, pu1;
    pu0.h2[0] = __builtin_amdgcn_cvt_pkrtz(p[0][0], p[0][1]);
    pu0.h2[1] = __builtin_amdgcn_cvt_pkrtz(p[0][2], p[0][3]);
    pu1.h2[0] = __builtin_amdgcn_cvt_pkrtz(p[1][0], p[1][1]);
    pu1.h2[1] = __builtin_amdgcn_cvt_pkrtz(p[1][2], p[1][3]);

#pragma unroll
    for (int dt = 0; dt < 16; ++dt) {
      const char* vrow = Vld + (dt * 16 + (lane & 15)) * 80 + 8 * gi;
      f16x4 v0 = *(const f16x4*)(vrow);
      f16x4 v1 = *(const f16x4*)(vrow + 32);
      acc[dt] = __builtin_amdgcn_mfma_f32_16x16x16f16(pu0.h4, v0, acc[dt], 0, 0, 0);
      acc[dt] = __builtin_amdgcn_mfma_f32_16x16x16f16(pu1.h4, v1, acc[dt], 0, 0, 0);
    }

    __syncthreads();
    if (t < NIT - 1) stage_write();
    __syncthreads();
  }

  if (g == 1) {
#pragma unroll
    for (int dt = 0; dt < 16; ++dt)
#pragma unroll
      for (int j = 0; j < 4; ++j)
        Cst[wq * 4096 + (gi * 4 + j) * 256 + dt * 16 + (lane & 15)] = acc[dt][j];
    if (lane < 16) {
      ml[(wq * 16 + lane) * 2 + 0] = mrun;
      ml[(wq * 16 + lane) * 2 + 1] = lrun;
    }
  }
  __syncthreads();
  if (g == 0) {
    float* Ob = Out + (size_t)b * NL * ND;
#pragma unroll
    for (int j = 0; j < 4; ++j) {
      const int rloc = gi * 4 + j;
      const float m0r = __shfl(mrun, rloc, 16);
      const float l0r = __shfl(lrun, rloc, 16);
      const float m1 = ml[(wq * 16 + rloc) * 2 + 0];
      const float l1 = ml[(wq * 16 + rloc) * 2 + 1];
      const float M = fmaxf(m0r, m1);
      const float c0 = __expf(m0r - M), c1 = __expf(m1 - M);
      const float inv = 1.f / (l0r * c0 + l1 * c1);
      const int row = qw + rloc;
#pragma unroll
      for (int dt = 0; dt < 16; ++dt) {
        const float o1 = Cst[wq * 4096 + rloc * 256 + dt * 16 + (lane & 15)];
        Ob[(size_t)row * ND + dt * 16 + (lane & 15)] = (acc[dt][j] * c0 + o1 * c1) * inv;
      }
    }
  }
}

extern "C" void kernel_launch(void* const* d_in, const int* in_sizes, int n_in,
                              void* d_out, int out_size, void* d_ws, size_t ws_size,
                              hipStream_t stream) {
  (void)in_sizes; (void)n_in; (void)out_size;
  const float* inQ = (const float*)d_in[0];
  const float* inK = (const float*)d_in[1];
  const float* inV = (const float*)d_in[2];
  const float* Wq = (const float*)d_in[3];
  const float* Wk = (const float*)d_in[4];
  const float* Wv = (const float*)d_in[5];
  float* out = (float*)d_out;

  // ws layout (f16): Qh,Kh,Vh [B*L*D]; WT [3*256*256]; QEh [B*L*L] (SKEWED);
  // Pac f16 [4][B*L][D]; then (f32) Pml [4][B*L][2].
  f16* ws = (f16*)d_ws;
  f16* Qh = ws;
  f16* Kh = Qh + (size_t)QKV_ELEMS;
  f16* Vh = Kh + (size_t)QKV_ELEMS;
  f16* WT = Vh + (size_t)QKV_ELEMS;
  f16* QEh = WT + 3 * 65536;
  f16* Pac = QEh + (size_t)NB * NL * NL;
  float* Pml = (float*)(Pac + (size_t)4 * QKV_ELEMS);
  const size_t need = (size_t)((char*)(Pml + 4 * NB * NL * 2) - (char*)d_ws);

  k0_wt<<<dim3(768), dim3(256), 0, stream>>>(Wq, Wk, Wv, WT);
  k1_proj<<<dim3(256, 3), dim3(256), 0, stream>>>(inQ, inK, inV, WT, Qh, Kh, Vh);
  k2_qe<<<dim3(16, 16, 8), dim3(256), 0, stream>>>(Qh, Kh, QEh);
  if (ws_size >= need) {
    k3_part<<<dim3(32, 8, 4), dim3(256), 2 * KVBUF, stream>>>(Qh, Kh, Vh, QEh, Pac, Pml);
    k4_comb<<<dim3(NB * NL / 4), dim3(256), 0, stream>>>(Pac, Pml, out);
  } else {
    k3_attn<<<dim3(32, 8), dim3(512), 73728, stream>>>(Qh, Kh, Vh, QEh, out);
  }
}

// Round 18
// 164.578 us; speedup vs baseline: 1.2661x; 1.1238x over previous
//
#include <hip/hip_runtime.h>
#include <hip/hip_fp16.h>
#include <stdint.h>

typedef _Float16 f16;
typedef _Float16 f16x2 __attribute__((ext_vector_type(2)));
typedef _Float16 f16x4 __attribute__((ext_vector_type(4)));
typedef _Float16 f16x8 __attribute__((ext_vector_type(8)));
typedef __fp16 fp16x2 __attribute__((ext_vector_type(2)));  // cvt_pkrtz return type
typedef float f32x4 __attribute__((ext_vector_type(4)));

#define NB 8
#define NL 2048
#define ND 256
#define QKV_ELEMS (NB * NL * ND)   // 4194304

__device__ __forceinline__ f32x4 mfma16(f16x8 a, f16x8 b, f32x4 c) {
  return __builtin_amdgcn_mfma_f32_16x16x32_f16(a, b, c, 0, 0, 0);
}

// ---------------- K0: transpose+convert weights: WT[m][n][k] = (f16)W_m[k][n]
__global__ void k0_wt(const float* __restrict__ Wq, const float* __restrict__ Wk,
                      const float* __restrict__ Wv, f16* __restrict__ WT) {
  int id = blockIdx.x * 256 + threadIdx.x;  // 0..196607
  int m = id >> 16;
  int r = id & 65535;
  int k = r >> 8, n = r & 255;
  const float* W = (m == 0) ? Wq : (m == 1) ? Wk : Wv;
  WT[m * 65536 + n * 256 + k] = (f16)W[k * 256 + n];
}

// ---------------- K1: projections (fp32 A, f16 MFMA, f16 out). 64 rows/block.
// (256,2): measured VGPR map (r7-r9) -- single-arg lets regalloc take ~168
// VGPR (3 waves/SIMD cap); arg=2 caps at 128 which this kernel fits.
__global__ __launch_bounds__(256, 2) void k1_proj(
    const float* __restrict__ Aq, const float* __restrict__ Ak, const float* __restrict__ Av,
    const f16* __restrict__ WT, f16* __restrict__ Qh, f16* __restrict__ Kh,
    f16* __restrict__ Vh) {
  const int m = blockIdx.y;
  const float* A = (m == 0) ? Aq : (m == 1) ? Ak : Av;
  f16* O = (m == 0) ? Qh : (m == 1) ? Kh : Vh;
  const f16* Wm = WT + m * 65536;
  const int row0 = blockIdx.x * 64;
  const int tid = threadIdx.x;
  const int lane = tid & 63, w = tid >> 6;

  __shared__ f16 Ald[64 * 64];    // [r][k], swizzled ((r&7)<<4) on byte offset
  __shared__ f16 Wld[256 * 64];   // [n][k], swizzled ((n&7)<<4)

  f32x4 acc[16];
#pragma unroll
  for (int i = 0; i < 16; ++i) acc[i] = f32x4{0.f, 0.f, 0.f, 0.f};

  for (int kb = 0; kb < 4; ++kb) {
    __syncthreads();
    {  // stage A tile 64x64 fp32 -> f16
      const int r = tid >> 2, c0 = (tid & 3) * 16;
      const float* src = A + (size_t)(row0 + r) * ND + kb * 64 + c0;
      f16x8 h0, h1;
#pragma unroll
      for (int j = 0; j < 8; ++j) h0[j] = (f16)src[j];
#pragma unroll
      for (int j = 0; j < 8; ++j) h1[j] = (f16)src[8 + j];
      const int sw = (r & 7) << 4;
      *(f16x8*)((char*)Ald + r * 128 + ((c0 * 2) ^ sw)) = h0;
      *(f16x8*)((char*)Ald + r * 128 + ((c0 * 2 + 16) ^ sw)) = h1;
    }
    {  // stage WT tile [256][64] f16
      const int n = tid;
      const f16* src = Wm + n * 256 + kb * 64;
      const int sw = (n & 7) << 4;
#pragma unroll
      for (int j = 0; j < 8; ++j) {
        f16x8 v = *(const f16x8*)(src + j * 8);
        *(f16x8*)((char*)Wld + n * 128 + ((j * 16) ^ sw)) = v;
      }
    }
    __syncthreads();
#pragma unroll
    for (int kk = 0; kk < 2; ++kk) {
      const int arow = w * 16 + (lane & 15);
      const int ko = kk * 64 + (lane >> 4) * 16;
      f16x8 a = *(const f16x8*)((char*)Ald + arow * 128 + (ko ^ ((arow & 7) << 4)));
#pragma unroll
      for (int nt = 0; nt < 16; ++nt) {
        const int n = nt * 16 + (lane & 15);
        f16x8 b = *(const f16x8*)((char*)Wld + n * 128 + (ko ^ ((n & 7) << 4)));
        acc[nt] = mfma16(a, b, acc[nt]);
      }
    }
  }
  const int rl = (lane >> 4) * 4;
#pragma unroll
  for (int nt = 0; nt < 16; ++nt) {
    const int col = nt * 16 + (lane & 15);
#pragma unroll
    for (int j = 0; j < 4; ++j)
      O[(size_t)(row0 + w * 16 + rl + j) * ND + col] = (f16)acc[nt][j];
  }
}

// ---------------- K2: Srel[b] = skew(Q[b] @ (K[b]-Q[b])^T), 128x128 tile.
// E = K - Q computed during B-tile staging. Epilogue writes each QE element
// DIRECTLY to its skew target (bijection):
//   QE[r][c] -> Srel[r][c+r-(L-1)]    if c >= L-1-r
//           -> Srel[r-1][c+r+1]       else (dropped when r==0)
// Only Srel[q][q+1] cells stay unwritten (the zero column; masked in k3).
// (256,2): cap VGPR at 128 (fits) -> 4 waves/SIMD possible vs ~168 single-arg.
__global__ __launch_bounds__(256, 2) void k2_qe(const f16* __restrict__ Qh,
                                                const f16* __restrict__ Kh,
                                                f16* __restrict__ QEh) {
  const int b = blockIdx.z;
  const int m0 = blockIdx.x * 128, n0 = blockIdx.y * 128;
  const int tid = threadIdx.x, lane = tid & 63, w = tid >> 6;
  const int wr = (w >> 1) * 64, wc = (w & 1) * 64;
  const f16* Qb = Qh + (size_t)b * NL * ND;
  const f16* Kb = Kh + (size_t)b * NL * ND;

  __shared__ f16 As[128 * 64];  // [r][k] swizzled ((r&7)<<4)
  __shared__ f16 Bs[128 * 64];

  f32x4 acc[4][4];
#pragma unroll
  for (int i = 0; i < 4; ++i)
#pragma unroll
    for (int j = 0; j < 4; ++j) acc[i][j] = f32x4{0.f, 0.f, 0.f, 0.f};

  for (int kb = 0; kb < 4; ++kb) {
    __syncthreads();
#pragma unroll
    for (int j = 0; j < 4; ++j) {
      const int c = j * 256 + tid;       // 1024 chunks of 16B
      const int r = c >> 3;
      const int ko = (c & 7) * 16;       // byte offset in row
      const int sw = (r & 7) << 4;
      f16x8 va = *(const f16x8*)((const char*)(Qb + (size_t)(m0 + r) * ND + kb * 64) + ko);
      *(f16x8*)((char*)As + r * 128 + (ko ^ sw)) = va;
      f16x8 vk = *(const f16x8*)((const char*)(Kb + (size_t)(n0 + r) * ND + kb * 64) + ko);
      f16x8 vq = *(const f16x8*)((const char*)(Qb + (size_t)(n0 + r) * ND + kb * 64) + ko);
      *(f16x8*)((char*)Bs + r * 128 + (ko ^ sw)) = vk - vq;  // E = K - Q
    }
    __syncthreads();
#pragma unroll
    for (int kk = 0; kk < 2; ++kk) {
      const int ko = kk * 64 + (lane >> 4) * 16;
      f16x8 a[4], bf[4];
#pragma unroll
      for (int mt = 0; mt < 4; ++mt) {
        const int r = wr + mt * 16 + (lane & 15);
        a[mt] = *(const f16x8*)((char*)As + r * 128 + (ko ^ ((r & 7) << 4)));
      }
#pragma unroll
      for (int nt = 0; nt < 4; ++nt) {
        const int r = wc + nt * 16 + (lane & 15);
        bf[nt] = *(const f16x8*)((char*)Bs + r * 128 + (ko ^ ((r & 7) << 4)));
      }
#pragma unroll
      for (int mt = 0; mt < 4; ++mt)
#pragma unroll
        for (int nt = 0; nt < 4; ++nt) acc[mt][nt] = mfma16(a[mt], bf[nt], acc[mt][nt]);
    }
  }
  f16* outb = QEh + (size_t)b * NL * NL;
#pragma unroll
  for (int mt = 0; mt < 4; ++mt)
#pragma unroll
    for (int nt = 0; nt < 4; ++nt) {
      const int col = n0 + wc + nt * 16 + (lane & 15);
#pragma unroll
      for (int j = 0; j < 4; ++j) {
        const int row = m0 + wr + mt * 16 + (lane >> 4) * 4 + j;
        int qrow, kk2;
        if (col >= (NL - 1) - row) { qrow = row; kk2 = col + row - (NL - 1); }
        else { qrow = row - 1; kk2 = col + row + 1; }
        if (qrow >= 0)
          outb[(size_t)qrow * NL + kk2] = (f16)acc[mt][nt][j];
      }
    }
}

// ---------------- K3p: 4-way key-split flash attention partials.
// dbuf K/V (one barrier/iter) + SKEWED-Srel row-contiguous gather (r17 win:
// 2x f16x4 vector loads/lane vs 8 scattered scalars; zero column masked).
#define KVBUF 36864   // 16384 (K [32][256] swz) + 20480 (V [256][40])
#define NITP 16
__global__ __launch_bounds__(256, 2) void k3_part(
    const f16* __restrict__ Qh, const f16* __restrict__ Kh, const f16* __restrict__ Vh,
    const f16* __restrict__ QEh, f16* __restrict__ Pac, float* __restrict__ Pml) {
  extern __shared__ char smem[];  // 2 * KVBUF = 73728 B
  const int b = blockIdx.y;
  const int g = blockIdx.z;
  const int q0 = blockIdx.x * 64;
  const int tid = threadIdx.x, lane = tid & 63, w = tid >> 6;
  const int qw = q0 + w * 16;
  const int gi = lane >> 4;

  const f16* Qb = Qh + (size_t)b * NL * ND;
  const f16* Kb = Kh + (size_t)b * NL * ND;
  const f16* Vb = Vh + (size_t)b * NL * ND;
  const f16* QEb = QEh + (size_t)b * NL * NL;  // skewed Srel layout

  f16x8 qf[8];
  {
    const int r = qw + (lane & 15);
#pragma unroll
    for (int kk = 0; kk < 8; ++kk)
      qf[kk] = *(const f16x8*)(Qb + (size_t)r * ND + kk * 32 + gi * 8);
  }

  f32x4 acc[16];
#pragma unroll
  for (int i = 0; i < 16; ++i) acc[i] = f32x4{0.f, 0.f, 0.f, 0.f};
  float mrun = -1e30f, lrun = 0.f;

  f16x8 kst[4], vst[4];
  const int kp = tid & 15, dch = tid >> 4;

  auto stage_load = [&](int t) {
    const f16* Ks = Kb + (size_t)(g * NITP + t) * 32 * ND;
#pragma unroll
    for (int j = 0; j < 4; ++j) {
      const int c = j * 256 + tid;
      kst[j] = *(const f16x8*)(Ks + (c >> 5) * ND + (c & 31) * 8);
    }
    const f16* Vs = Vb + (size_t)(g * NITP + t) * 32 * ND;
    vst[0] = *(const f16x8*)(Vs + (2 * kp) * ND + dch * 16);
    vst[1] = *(const f16x8*)(Vs + (2 * kp) * ND + dch * 16 + 8);
    vst[2] = *(const f16x8*)(Vs + (2 * kp + 1) * ND + dch * 16);
    vst[3] = *(const f16x8*)(Vs + (2 * kp + 1) * ND + dch * 16 + 8);
  };
  auto stage_write = [&](int buf) {
    char* Kld = smem + buf * KVBUF;
    char* Vld = Kld + 16384;
#pragma unroll
    for (int j = 0; j < 4; ++j) {
      const int c = j * 256 + tid;
      const int key = c >> 5, d0 = (c & 31) * 16;
      *(f16x8*)(Kld + key * 512 + (d0 ^ ((key & 7) << 4))) = kst[j];
    }
#pragma unroll
    for (int jj = 0; jj < 16; ++jj) {
      f16x2 pr;
      pr.x = (jj < 8) ? vst[0][jj & 7] : vst[1][jj & 7];  // key 2*kp
      pr.y = (jj < 8) ? vst[2][jj & 7] : vst[3][jj & 7];  // key 2*kp+1
      *(f16x2*)(Vld + (dch * 16 + jj) * 80 + kp * 4) = pr;
    }
  };

  stage_load(0);
  stage_write(0);
  __syncthreads();

  const int qa = qw + (lane & 15);

  for (int t = 0; t < NITP; ++t) {
    const int cur = t & 1;
    const int k0 = (g * NITP + t) * 32;

    // srel gather: ROW-CONTIGUOUS from skewed Srel (2 vector loads/lane)
    float srel[2][4];
#pragma unroll
    for (int nt = 0; nt < 2; ++nt) {
      const int kb2 = k0 + nt * 16 + gi * 4;
      f16x4 v4 = *(const f16x4*)(QEb + (size_t)qa * NL + kb2);
#pragma unroll
      for (int j = 0; j < 4; ++j)
        srel[nt][j] = (kb2 + j == qa + 1) ? 0.f : (float)v4[j];
    }

    if (t < NITP - 1) stage_load(t + 1);

    const char* Kld = smem + cur * KVBUF;
    const char* Vld = Kld + 16384;

    f32x4 s[2] = {f32x4{0.f, 0.f, 0.f, 0.f}, f32x4{0.f, 0.f, 0.f, 0.f}};
#pragma unroll
    for (int kk = 0; kk < 8; ++kk) {
      const int ko = kk * 64 + gi * 16;
#pragma unroll
      for (int nt = 0; nt < 2; ++nt) {
        const int key = nt * 16 + (lane & 15);
        f16x8 af = *(const f16x8*)(Kld + key * 512 + (ko ^ ((key & 7) << 4)));
        s[nt] = mfma16(af, qf[kk], s[nt]);
      }
    }

    float sv[2][4];
#pragma unroll
    for (int nt = 0; nt < 2; ++nt)
#pragma unroll
      for (int j = 0; j < 4; ++j) sv[nt][j] = 0.0625f * (s[nt][j] + srel[nt][j]);

    float pm = fmaxf(fmaxf(fmaxf(sv[0][0], sv[0][1]), fmaxf(sv[0][2], sv[0][3])),
                     fmaxf(fmaxf(sv[1][0], sv[1][1]), fmaxf(sv[1][2], sv[1][3])));
    pm = fmaxf(pm, __shfl_xor(pm, 16, 64));
    pm = fmaxf(pm, __shfl_xor(pm, 32, 64));

    float p[2][4];
    if (__any(pm > mrun + 8.f)) {
      const float mn = fmaxf(mrun, pm);
      const float al = __expf(mrun - mn);
      mrun = mn;
#pragma unroll
      for (int nt = 0; nt < 2; ++nt)
#pragma unroll
        for (int j = 0; j < 4; ++j) p[nt][j] = __expf(sv[nt][j] - mrun);
      float rs = (p[0][0] + p[0][1]) + (p[0][2] + p[0][3]) +
                 (p[1][0] + p[1][1]) + (p[1][2] + p[1][3]);
      rs += __shfl_xor(rs, 16, 64);
      rs += __shfl_xor(rs, 32, 64);
      lrun = lrun * al + rs;
#pragma unroll
      for (int j = 0; j < 4; ++j) {
        const float aj = __shfl(al, gi * 4 + j, 16);
#pragma unroll
        for (int dt = 0; dt < 16; ++dt) acc[dt][j] *= aj;
      }
    } else {
#pragma unroll
      for (int nt = 0; nt < 2; ++nt)
#pragma unroll
        for (int j = 0; j < 4; ++j) p[nt][j] = __expf(sv[nt][j] - mrun);
      float rs = (p[0][0] + p[0][1]) + (p[0][2] + p[0][3]) +
                 (p[1][0] + p[1][1]) + (p[1][2] + p[1][3]);
      rs += __shfl_xor(rs, 16, 64);
      rs += __shfl_xor(rs, 32, 64);
      lrun += rs;
    }

    union {
      fp16x2 h2[2];
      f16x4 h4;
    } pu0, pu1;
    pu0.h2[0] = __builtin_amdgcn_cvt_pkrtz(p[0][0], p[0][1]);
    pu0.h2[1] = __builtin_amdgcn_cvt_pkrtz(p[0][2], p[0][3]);
    pu1.h2[0] = __builtin_amdgcn_cvt_pkrtz(p[1][0], p[1][1]);
    pu1.h2[1] = __builtin_amdgcn_cvt_pkrtz(p[1][2], p[1][3]);

#pragma unroll
    for (int dt = 0; dt < 16; ++dt) {
      const char* vrow = Vld + (dt * 16 + (lane & 15)) * 80 + 8 * gi;
      f16x4 v0 = *(const f16x4*)(vrow);
      f16x4 v1 = *(const f16x4*)(vrow + 32);
      acc[dt] = __builtin_amdgcn_mfma_f32_16x16x16f16(pu0.h4, v0, acc[dt], 0, 0, 0);
      acc[dt] = __builtin_amdgcn_mfma_f32_16x16x16f16(pu1.h4, v1, acc[dt], 0, 0, 0);
    }

    if (t < NITP - 1) stage_write(cur ^ 1);  // other buffer: no reader this iter
    __syncthreads();                         // publish + fence before reuse
  }

  // ---- write l-normalized partials (f16) ----
  const float inv = 1.f / lrun;
  f16* Pb = Pac + ((size_t)g * (NB * NL) + (size_t)b * NL) * ND;
#pragma unroll
  for (int j = 0; j < 4; ++j) {
    const float invj = __shfl(inv, gi * 4 + j, 16);
    const int row = qw + gi * 4 + j;
#pragma unroll
    for (int dt = 0; dt < 16; ++dt)
      Pb[(size_t)row * ND + dt * 16 + (lane & 15)] = (f16)(acc[dt][j] * invj);
  }
  if (lane < 16) {
    const size_t r = (size_t)g * (NB * NL) + (size_t)b * NL + qw + lane;
    Pml[r * 2 + 0] = mrun;
    Pml[r * 2 + 1] = lrun;
  }
}

// ---------------- K4: combine 4 key-group normalized partials -> output
__global__ __launch_bounds__(256) void k4_comb(const f16* __restrict__ Pac,
                                               const float* __restrict__ Pml,
                                               float* __restrict__ Out) {
  const int row = blockIdx.x * 4 + (threadIdx.x >> 6);
  const int lane = threadIdx.x & 63;
  float m[4], l[4];
#pragma unroll
  for (int gq = 0; gq < 4; ++gq) {
    const size_t r = (size_t)gq * (NB * NL) + row;
    m[gq] = Pml[r * 2 + 0];
    l[gq] = Pml[r * 2 + 1];
  }
  const float M = fmaxf(fmaxf(m[0], m[1]), fmaxf(m[2], m[3]));
  float wgt[4];
  float denom = 0.f;
#pragma unroll
  for (int gq = 0; gq < 4; ++gq) {
    wgt[gq] = l[gq] * __expf(m[gq] - M);
    denom += wgt[gq];
  }
  const float inv = 1.f / denom;
  const size_t base = (size_t)row * ND + lane * 4;
  float o[4] = {0.f, 0.f, 0.f, 0.f};
#pragma unroll
  for (int gq = 0; gq < 4; ++gq) {
    f16x4 p = *(const f16x4*)(Pac + (size_t)gq * (NB * NL) * ND + base);
    const float s = wgt[gq] * inv;
#pragma unroll
    for (int e = 0; e < 4; ++e) o[e] += (float)p[e] * s;
  }
  f32x4 ov = {o[0], o[1], o[2], o[3]};
  *(f32x4*)(Out + base) = ov;
}

// ---------------- K3 fallback (r6 form, skewed-Srel gather), for small ws.
#define NIT 32
__global__ __launch_bounds__(512, 2) void k3_attn(
    const f16* __restrict__ Qh, const f16* __restrict__ Kh, const f16* __restrict__ Vh,
    const f16* __restrict__ QEh, float* __restrict__ Out) {
  extern __shared__ char smemd[];  // 73728 B
  const int b = blockIdx.y;
  const int q0 = blockIdx.x * 64;
  const int tid = threadIdx.x, lane = tid & 63, w = tid >> 6;
  const int g = w >> 2, wq = w & 3;
  const int qw = q0 + wq * 16;
  const int lt = tid & 255;
  const int gi = lane >> 4;

  float* Cst = (float*)smemd;
  float* ml = (float*)(smemd + 65536);

  const f16* Qb = Qh + (size_t)b * NL * ND;
  const f16* Kb = Kh + (size_t)b * NL * ND;
  const f16* Vb = Vh + (size_t)b * NL * ND;
  const f16* QEb = QEh + (size_t)b * NL * NL;  // skewed Srel layout

  f16x8 qf[8];
  {
    const int r = qw + (lane & 15);
#pragma unroll
    for (int kk = 0; kk < 8; ++kk)
      qf[kk] = *(const f16x8*)(Qb + (size_t)r * ND + kk * 32 + gi * 8);
  }

  f32x4 acc[16];
#pragma unroll
  for (int i = 0; i < 16; ++i) acc[i] = f32x4{0.f, 0.f, 0.f, 0.f};
  float mrun = -1e30f, lrun = 0.f;

  f16x8 kst[4], vst[4];
  const int kp = lt & 15, dch = lt >> 4;

  auto stage_load = [&](int t) {
    const f16* Ks = Kb + (size_t)(g * NIT + t) * 32 * ND;
#pragma unroll
    for (int j = 0; j < 4; ++j) {
      const int c = j * 256 + lt;
      kst[j] = *(const f16x8*)(Ks + (c >> 5) * ND + (c & 31) * 8);
    }
    const f16* Vs = Vb + (size_t)(g * NIT + t) * 32 * ND;
    vst[0] = *(const f16x8*)(Vs + (2 * kp) * ND + dch * 16);
    vst[1] = *(const f16x8*)(Vs + (2 * kp) * ND + dch * 16 + 8);
    vst[2] = *(const f16x8*)(Vs + (2 * kp + 1) * ND + dch * 16);
    vst[3] = *(const f16x8*)(Vs + (2 * kp + 1) * ND + dch * 16 + 8);
  };
  auto stage_write = [&]() {
    char* Kld = smemd + g * KVBUF;
    char* Vld = Kld + 16384;
#pragma unroll
    for (int j = 0; j < 4; ++j) {
      const int c = j * 256 + lt;
      const int key = c >> 5, d0 = (c & 31) * 16;
      *(f16x8*)(Kld + key * 512 + (d0 ^ ((key & 7) << 4))) = kst[j];
    }
#pragma unroll
    for (int jj = 0; jj < 16; ++jj) {
      f16x2 pr;
      pr.x = (jj < 8) ? vst[0][jj & 7] : vst[1][jj & 7];
      pr.y = (jj < 8) ? vst[2][jj & 7] : vst[3][jj & 7];
      *(f16x2*)(Vld + (dch * 16 + jj) * 80 + kp * 4) = pr;
    }
  };

  stage_load(0);
  stage_write();
  __syncthreads();

  const int qa = qw + (lane & 15);

  for (int t = 0; t < NIT; ++t) {
    const int k0 = (g * NIT + t) * 32;

    float srel[2][4];
#pragma unroll
    for (int nt = 0; nt < 2; ++nt) {
      const int kb2 = k0 + nt * 16 + gi * 4;
      f16x4 v4 = *(const f16x4*)(QEb + (size_t)qa * NL + kb2);
#pragma unroll
      for (int j = 0; j < 4; ++j)
        srel[nt][j] = (kb2 + j == qa + 1) ? 0.f : (float)v4[j];
    }

    if (t < NIT - 1) stage_load(t + 1);

    const char* Kld = smemd + g * KVBUF;
    const char* Vld = Kld + 16384;

    f32x4 s[2] = {f32x4{0.f, 0.f, 0.f, 0.f}, f32x4{0.f, 0.f, 0.f, 0.f}};
#pragma unroll
    for (int kk = 0; kk < 8; ++kk) {
      const int ko = kk * 64 + gi * 16;
#pragma unroll
      for (int nt = 0; nt < 2; ++nt) {
        const int key = nt * 16 + (lane & 15);
        f16x8 af = *(const f16x8*)(Kld + key * 512 + (ko ^ ((key & 7) << 4)));
        s[nt] = mfma16(af, qf[kk], s[nt]);
      }
    }

    float sv[2][4];
#pragma unroll
    for (int nt = 0; nt < 2; ++nt)
#pragma unroll
      for (int j = 0; j < 4; ++j) sv[nt][j] = 0.0625f * (s[nt][j] + srel[nt][j]);

    float pm = fmaxf(fmaxf(fmaxf(sv[0][0], sv[0][1]), fmaxf(sv[0][2], sv[0][3])),
                     fmaxf(fmaxf(sv[1][0], sv[1][1]), fmaxf(sv[1][2], sv[1][3])));
    pm = fmaxf(pm, __shfl_xor(pm, 16, 64));
    pm = fmaxf(pm, __shfl_xor(pm, 32, 64));

    float p[2][4];
    if (__any(pm > mrun + 8.f)) {
      const float mn = fmaxf(mrun, pm);
      const float al = __expf(mrun - mn);
      mrun = mn;
#pragma unroll
      for (int nt = 0; nt < 2; ++nt)
#pragma unroll
        for (int j = 0; j < 4; ++j) p[nt][j] = __expf(sv[nt][j] - mrun);
      float rs = (p[0][0] + p[0][1]) + (p[0][2] + p[0][3]) +
                 (p[1][0] + p[1][1]) + (p[1][2] + p[1][3]);
      rs += __shfl_xor(rs, 16, 64);
      rs += __shfl_xor(rs, 32, 64);
      lrun = lrun * al + rs;
#pragma unroll
      for (int j = 0; j < 4; ++j) {
        const float aj = __shfl(al, gi * 4 + j, 16);
#pragma unroll
        for (int dt = 0; dt < 16; ++dt) acc[dt][j] *= aj;
      }
    } else {
#pragma unroll
      for (int nt = 0; nt < 2; ++nt)
#pragma unroll
        for (int j = 0; j < 4; ++j) p[nt][j] = __expf(sv[nt][j] - mrun);
      float rs = (p[0][0] + p[0][1]) + (p[0][2] + p[0][3]) +
                 (p[1][0] + p[1][1]) + (p[1][2] + p[1][3]);
      rs += __shfl_xor(rs, 16, 64);
      rs += __shfl_xor(rs, 32, 64);
      lrun += rs;
    }

    union {
      fp16x2 h2[2];
      f16x4 h4;
    } pu0, pu1;
    pu0.h2[0] = __builtin_amdgcn_cvt_pkrtz(p[0][0], p[0][1]);
    pu0.h2[1] = __builtin_amdgcn_cvt_pkrtz(p[0][2], p[0][3]);
    pu1.h2[0] = __builtin_amdgcn_cvt_pkrtz(p[1][0], p[1][1]);
    pu1.h2[1] = __builtin_amdgcn_cvt_pkrtz(p[1][2], p[1][3]);

#pragma unroll
    for (int dt = 0; dt < 16; ++dt) {
      const char* vrow = Vld + (dt * 16 + (lane & 15)) * 80 + 8 * gi;
      f16x4 v0 = *(const f16x4*)(vrow);
      f16x4 v1 = *(const f16x4*)(vrow + 32);
      acc[dt] = __builtin_amdgcn_mfma_f32_16x16x16f16(pu0.h4, v0, acc[dt], 0, 0, 0);
      acc[dt] = __builtin_amdgcn_mfma_f32_16x16x16f16(pu1.h4, v1, acc[dt], 0, 0, 0);
    }

    __syncthreads();
    if (t < NIT - 1) stage_write();
    __syncthreads();
  }

  if (g == 1) {
#pragma unroll
    for (int dt = 0; dt < 16; ++dt)
#pragma unroll
      for (int j = 0; j < 4; ++j)
        Cst[wq * 4096 + (gi * 4 + j) * 256 + dt * 16 + (lane & 15)] = acc[dt][j];
    if (lane < 16) {
      ml[(wq * 16 + lane) * 2 + 0] = mrun;
      ml[(wq * 16 + lane) * 2 + 1] = lrun;
    }
  }
  __syncthreads();
  if (g == 0) {
    float* Ob = Out + (size_t)b * NL * ND;
#pragma unroll
    for (int j = 0; j < 4; ++j) {
      const int rloc = gi * 4 + j;
      const float m0r = __shfl(mrun, rloc, 16);
      const float l0r = __shfl(lrun, rloc, 16);
      const float m1 = ml[(wq * 16 + rloc) * 2 + 0];
      const float l1 = ml[(wq * 16 + rloc) * 2 + 1];
      const float M = fmaxf(m0r, m1);
      const float c0 = __expf(m0r - M), c1 = __expf(m1 - M);
      const float inv = 1.f / (l0r * c0 + l1 * c1);
      const int row = qw + rloc;
#pragma unroll
      for (int dt = 0; dt < 16; ++dt) {
        const float o1 = Cst[wq * 4096 + rloc * 256 + dt * 16 + (lane & 15)];
        Ob[(size_t)row * ND + dt * 16 + (lane & 15)] = (acc[dt][j] * c0 + o1 * c1) * inv;
      }
    }
  }
}

extern "C" void kernel_launch(void* const* d_in, const int* in_sizes, int n_in,
                              void* d_out, int out_size, void* d_ws, size_t ws_size,
                              hipStream_t stream) {
  (void)in_sizes; (void)n_in; (void)out_size;
  const float* inQ = (const float*)d_in[0];
  const float* inK = (const float*)d_in[1];
  const float* inV = (const float*)d_in[2];
  const float* Wq = (const float*)d_in[3];
  const float* Wk = (const float*)d_in[4];
  const float* Wv = (const float*)d_in[5];
  float* out = (float*)d_out;

  // ws layout (f16): Qh,Kh,Vh [B*L*D]; WT [3*256*256]; QEh [B*L*L] (SKEWED);
  // Pac f16 [4][B*L][D]; then (f32) Pml [4][B*L][2].
  f16* ws = (f16*)d_ws;
  f16* Qh = ws;
  f16* Kh = Qh + (size_t)QKV_ELEMS;
  f16* Vh = Kh + (size_t)QKV_ELEMS;
  f16* WT = Vh + (size_t)QKV_ELEMS;
  f16* QEh = WT + 3 * 65536;
  f16* Pac = QEh + (size_t)NB * NL * NL;
  float* Pml = (float*)(Pac + (size_t)4 * QKV_ELEMS);
  const size_t need = (size_t)((char*)(Pml + 4 * NB * NL * 2) - (char*)d_ws);

  k0_wt<<<dim3(768), dim3(256), 0, stream>>>(Wq, Wk, Wv, WT);
  k1_proj<<<dim3(256, 3), dim3(256), 0, stream>>>(inQ, inK, inV, WT, Qh, Kh, Vh);
  k2_qe<<<dim3(16, 16, 8), dim3(256), 0, stream>>>(Qh, Kh, QEh);
  if (ws_size >= need) {
    k3_part<<<dim3(32, 8, 4), dim3(256), 2 * KVBUF, stream>>>(Qh, Kh, Vh, QEh, Pac, Pml);
    k4_comb<<<dim3(NB * NL / 4), dim3(256), 0, stream>>>(Pac, Pml, out);
  } else {
    k3_attn<<<dim3(32, 8), dim3(512), 73728, stream>>>(Qh, Kh, Vh, QEh, out);
  }
}